// Round 7
// baseline (164.777 us; speedup 1.0000x reference)
//
#include <hip/hip_runtime.h>

// Problem constants
#define B_  2
#define S_  1024
#define FIN 768
#define E_  768
#define H_  12
#define DH  64   // = FH = 64

typedef unsigned int uint;
typedef unsigned short ushort;
typedef __attribute__((ext_vector_type(8))) short short8;    // 8 bf16 (4 VGPRs)
typedef __attribute__((ext_vector_type(4))) float floatx4;   // MFMA acc

__device__ __forceinline__ ushort f2bf(float f) {   // RNE float->bf16 bits
    uint u = __float_as_uint(f);
    return (ushort)((u + 0x7fffu + ((u >> 16) & 1u)) >> 16);
}

__device__ __forceinline__ uint4 pack8(const ushort* p) {
    uint4 r;
    r.x = (uint)p[0] | ((uint)p[1] << 16);
    r.y = (uint)p[2] | ((uint)p[3] << 16);
    r.z = (uint)p[4] | ((uint)p[5] << 16);
    r.w = (uint)p[6] | ((uint)p[7] << 16);
    return r;
}

__device__ __forceinline__ void split8v(float4 a, float4 b, short8& hi, short8& lo) {
    float v[8] = {a.x, a.y, a.z, a.w, b.x, b.y, b.z, b.w};
    ushort h[8], l[8];
#pragma unroll
    for (int j = 0; j < 8; ++j) {
        h[j] = f2bf(v[j]);
        l[j] = f2bf(v[j] - __uint_as_float(((uint)h[j]) << 16));
    }
    uint4 H = pack8(h), L = pack8(l);
    hi = *(short8*)&H;
    lo = *(short8*)&L;
}

// ---------------------------------------------------------------------------
// K0: conversion + prep pass. blocks 0..767: xs -> xsH/xsL bf16 split planes.
// blocks 768..1055: ew -> ewH/ewL. block 1056: W-prep (Wn, r1inv, Wfrag).
// ---------------------------------------------------------------------------
__global__ __launch_bounds__(256) void k_conv(const float* __restrict__ xs,
                                              const float* __restrict__ ew,
                                              const float* __restrict__ nw,
                                              ushort* __restrict__ xsH,
                                              ushort* __restrict__ xsL,
                                              ushort* __restrict__ ewH,
                                              ushort* __restrict__ ewL,
                                              float* __restrict__ Wn,
                                              float* __restrict__ r1inv,
                                              ushort* __restrict__ Wfrag) {
    __shared__ float Wl[64 * 65];
    const int tid = threadIdx.x, bid = blockIdx.x;

    if (bid < 768) {          // xs conversion: 2048x768 / 8 per thread
        const size_t i = ((size_t)bid * 256 + tid) * 8;
        short8 hi, lo;
        split8v(*(const float4*)(xs + i), *(const float4*)(xs + i + 4), hi, lo);
        *(short8*)(xsH + i) = hi;
        *(short8*)(xsL + i) = lo;
        return;
    }
    if (bid < 1056) {         // ew conversion: 768x768 / 8 per thread
        const size_t i = ((size_t)(bid - 768) * 256 + tid) * 8;
        short8 hi, lo;
        split8v(*(const float4*)(ew + i), *(const float4*)(ew + i + 4), hi, lo);
        *(short8*)(ewH + i) = hi;
        *(short8*)(ewL + i) = lo;
        return;
    }

    // ---- prep block (bid == 1056) ----
    const int f = tid >> 2, q = tid & 3;
    float v[16];
    float s = 0.f;
#pragma unroll
    for (int i = 0; i < 16; ++i) { v[i] = nw[f * 64 + q * 16 + i]; s += v[i]; }
    s += __shfl_xor(s, 1, 64);
    s += __shfl_xor(s, 2, 64);
    const float inv = 1.f / fmaxf(s, 1e-20f);
    float w[16];
#pragma unroll
    for (int i = 0; i < 16; ++i) {
        w[i] = v[i] * inv;
        Wn[f * 64 + q * 16 + i] = w[i];
        Wl[f * 65 + q * 16 + i] = w[i];
    }
    __syncthreads();
    if (tid < 64) {
        float cs = 0.f;
        for (int ff = 0; ff < 64; ++ff) cs += Wl[ff * 65 + tid];
        float t = fmaxf(cs * (1.f / 64.f), 1e-6f);
        float S = t;
#pragma unroll
        for (int m = 1; m < 64; m <<= 1) S += __shfl_xor(S, m, 64);
        S = fmaxf(S, 1e-20f);
        r1inv[tid] = S / t;   // 1/rec1
    }
    // Ww planes (rows of Wn) from registers: row f, quarter q
    {
        short8 h0, l0, h1, l1;
        split8v(make_float4(w[0], w[1], w[2], w[3]),
                make_float4(w[4], w[5], w[6], w[7]), h0, l0);
        split8v(make_float4(w[8], w[9], w[10], w[11]),
                make_float4(w[12], w[13], w[14], w[15]), h1, l1);
        ushort* WwH = Wfrag + 2 * 4096;
        ushort* WwL = Wfrag + 3 * 4096;
        *(short8*)(WwH + f * 64 + q * 16) = h0;
        *(short8*)(WwH + f * 64 + q * 16 + 8) = h1;
        *(short8*)(WwL + f * 64 + q * 16) = l0;
        *(short8*)(WwL + f * 64 + q * 16 + 8) = l1;
    }
    // Wt planes (rows of WnT) from LDS: WnT[f][q*16+i] = Wn[q*16+i][f]
    {
        float t[16];
#pragma unroll
        for (int i = 0; i < 16; ++i) t[i] = Wl[(q * 16 + i) * 65 + f];
        short8 h0, l0, h1, l1;
        split8v(make_float4(t[0], t[1], t[2], t[3]),
                make_float4(t[4], t[5], t[6], t[7]), h0, l0);
        split8v(make_float4(t[8], t[9], t[10], t[11]),
                make_float4(t[12], t[13], t[14], t[15]), h1, l1);
        ushort* WtH = Wfrag;
        ushort* WtL = Wfrag + 4096;
        *(short8*)(WtH + f * 64 + q * 16) = h0;
        *(short8*)(WtH + f * 64 + q * 16 + 8) = h1;
        *(short8*)(WtL + f * 64 + q * 16) = l0;
        *(short8*)(WtL + f * 64 + q * 16 + 8) = l1;
    }
}

// ---------------------------------------------------------------------------
// K1: MFMA embed, 768 blocks (32 tok x 64 out = 1 head; head-fastest for L2
// x-reuse). ZERO-LDS K-loop: fragments loaded directly from the pre-converted
// bf16 planes (L1/L2-hot), no barriers, no staging. Wave = 16 tok x 32 out.
// ---------------------------------------------------------------------------
__global__ __launch_bounds__(256) void k_embed(const ushort* __restrict__ xsH,
                                               const ushort* __restrict__ xsL,
                                               const ushort* __restrict__ ewH,
                                               const ushort* __restrict__ ewL,
                                               const float* __restrict__ eb,
                                               float* __restrict__ inp) {
    __shared__ float RS[64];
    const int tid = threadIdx.x;
    const int bid = blockIdx.x;

    const int head = bid % 12;           // fastest -> consecutive blocks share x-tile
    const int tok0 = (bid / 12) * 32;

    const int wv = tid >> 6, lane = tid & 63;
    const int mbase = (wv >> 1) * 16;    // 16-token frag row
    const int nbase = (wv & 1) * 32;     // 32-out half
    const int lm = lane & 15, lq = lane >> 4;

    // dual accumulators: accA = hi*hi chain, accB = cross-term chain (ILP)
    floatx4 accA[2], accB[2];
    accA[0] = (floatx4)0.f; accA[1] = (floatx4)0.f;
    accB[0] = (floatx4)0.f; accB[1] = (floatx4)0.f;

    // fragment base pointers: lane (lm,lq) reads row r, k = k0 + lq*8
    const size_t xrow = (size_t)(tok0 + mbase + lm) * FIN;
    const size_t w0row = (size_t)(head * 64 + nbase + lm) * FIN;
    const size_t w1row = (size_t)(head * 64 + nbase + 16 + lm) * FIN;
    const ushort* xh  = xsH + xrow + lq * 8;
    const ushort* xl  = xsL + xrow + lq * 8;
    const ushort* w0h = ewH + w0row + lq * 8;
    const ushort* w0l = ewL + w0row + lq * 8;
    const ushort* w1h = ewH + w1row + lq * 8;
    const ushort* w1l = ewL + w1row + lq * 8;

#pragma unroll 4
    for (int k0 = 0; k0 < FIN; k0 += 32) {
        short8 ah  = *(const short8*)(xh + k0);
        short8 al  = *(const short8*)(xl + k0);
        short8 b0h = *(const short8*)(w0h + k0);
        short8 b0l = *(const short8*)(w0l + k0);
        short8 b1h = *(const short8*)(w1h + k0);
        short8 b1l = *(const short8*)(w1l + k0);
        accA[0] = __builtin_amdgcn_mfma_f32_16x16x32_bf16(ah, b0h, accA[0], 0, 0, 0);
        accB[0] = __builtin_amdgcn_mfma_f32_16x16x32_bf16(al, b0h, accB[0], 0, 0, 0);
        accB[0] = __builtin_amdgcn_mfma_f32_16x16x32_bf16(ah, b0l, accB[0], 0, 0, 0);
        accA[1] = __builtin_amdgcn_mfma_f32_16x16x32_bf16(ah, b1h, accA[1], 0, 0, 0);
        accB[1] = __builtin_amdgcn_mfma_f32_16x16x32_bf16(al, b1h, accB[1], 0, 0, 0);
        accB[1] = __builtin_amdgcn_mfma_f32_16x16x32_bf16(ah, b1l, accB[1], 0, 0, 0);
    }

    // epilogue: bias, clamp, per-token l1norm over 64 outs, store.
    const float b0 = eb[head * 64 + nbase + lm];
    const float b1 = eb[head * 64 + nbase + 16 + lm];
    float xe[2][4];
    float rs[4];
#pragma unroll
    for (int r = 0; r < 4; ++r) {
        float e0 = fmaxf((accA[0][r] + accB[0][r]) + b0, 1e-6f);
        float e1 = fmaxf((accA[1][r] + accB[1][r]) + b1, 1e-6f);
        xe[0][r] = e0; xe[1][r] = e1;
        float p = e0 + e1;
        p += __shfl_xor(p, 1, 64);
        p += __shfl_xor(p, 2, 64);
        p += __shfl_xor(p, 4, 64);
        p += __shfl_xor(p, 8, 64);
        rs[r] = p;
    }
    if (lm == 0) {
#pragma unroll
        for (int r = 0; r < 4; ++r)
            RS[(wv & 1) * 32 + mbase + lq * 4 + r] = rs[r];
    }
    __syncthreads();
    const size_t obase = ((size_t)((tok0 >> 10) * 12 + head) * 1024 + (tok0 & 1023));
#pragma unroll
    for (int r = 0; r < 4; ++r) {
        const int m = mbase + lq * 4 + r;
        const float inv = 1.f / fmaxf(RS[m] + RS[32 + m], 1e-20f);
        float* op = inp + (obase + m) * 64;
        op[nbase + lm]      = xe[0][r] * inv;
        op[nbase + 16 + lm] = xe[1][r] * inv;
    }
}

// ---------------------------------------------------------------------------
// helper: 64x64 matvec via MFMA with split-bf16 B planes in LDS (wave-private T)
// dual accumulator chains for ILP.
// ---------------------------------------------------------------------------
__device__ __forceinline__ void mfma_matvec(const float srcC[4][4], float* T,
                                            int lm, int lq,
                                            const ushort* WH, const ushort* WL,
                                            floatx4 out[4]) {
    __builtin_amdgcn_wave_barrier();
#pragma unroll
    for (int nt = 0; nt < 4; ++nt)
#pragma unroll
        for (int r = 0; r < 4; ++r)
            T[(lq * 4 + r) * 68 + nt * 16 + lm] = srcC[nt][r];
    __builtin_amdgcn_wave_barrier();
    float4 a00 = *(const float4*)&T[lm * 68 + lq * 8];
    float4 a01 = *(const float4*)&T[lm * 68 + lq * 8 + 4];
    float4 a10 = *(const float4*)&T[lm * 68 + 32 + lq * 8];
    float4 a11 = *(const float4*)&T[lm * 68 + 32 + lq * 8 + 4];
    __builtin_amdgcn_wave_barrier();
    short8 A0h, A0l, A1h, A1l;
    split8v(a00, a01, A0h, A0l);
    split8v(a10, a11, A1h, A1l);
#pragma unroll
    for (int nt = 0; nt < 4; ++nt) {
        const int row = (nt * 16 + lm) * 72;
        short8 b0h = *(const short8*)&WH[row + lq * 8];
        short8 b0l = *(const short8*)&WL[row + lq * 8];
        short8 b1h = *(const short8*)&WH[row + 32 + lq * 8];
        short8 b1l = *(const short8*)&WL[row + 32 + lq * 8];
        floatx4 acc0 = (floatx4)0.f, acc1 = (floatx4)0.f;
        acc0 = __builtin_amdgcn_mfma_f32_16x16x32_bf16(A0h, b0h, acc0, 0, 0, 0);
        acc0 = __builtin_amdgcn_mfma_f32_16x16x32_bf16(A0l, b0h, acc0, 0, 0, 0);
        acc0 = __builtin_amdgcn_mfma_f32_16x16x32_bf16(A0h, b0l, acc0, 0, 0, 0);
        acc1 = __builtin_amdgcn_mfma_f32_16x16x32_bf16(A1h, b1h, acc1, 0, 0, 0);
        acc1 = __builtin_amdgcn_mfma_f32_16x16x32_bf16(A1l, b1h, acc1, 0, 0, 0);
        acc1 = __builtin_amdgcn_mfma_f32_16x16x32_bf16(A1h, b1l, acc1, 0, 0, 0);
        out[nt] = acc0 + acc1;
    }
}

// ---------------------------------------------------------------------------
// K3: NNMF updates, 16 tokens per wave, 384 blocks x 4 waves.
// W fragment planes are pre-built (k_conv) — staging is a pure copy.
// ---------------------------------------------------------------------------
__global__ __launch_bounds__(256) void k_nnmf(const float* __restrict__ inp,
                                              const ushort* __restrict__ Wfrag,
                                              const float* __restrict__ r1inv,
                                              float* __restrict__ hout,
                                              float* __restrict__ hriout,
                                              float* __restrict__ mp0) {
    __shared__ ushort WtH[64 * 72], WtL[64 * 72];
    __shared__ ushort WwH[64 * 72], WwL[64 * 72];
    __shared__ float Tb[4][16 * 68];
    __shared__ float pbuf[256];
    const int tid = threadIdx.x, wv = tid >> 6, lane = tid & 63;
    const int lm = lane & 15, lq = lane >> 4;
    float* T = Tb[wv];
    const int rowbase = blockIdx.x * 64 + wv * 16;

    {   // stage W planes: pure copy, thread -> row tid>>2, k-quarter (tid&3)*16
        const int row = tid >> 2, kq = (tid & 3) * 16;
        const int g = row * 64 + kq, l = row * 72 + kq;
        *(short8*)&WtH[l]     = *(const short8*)(Wfrag + g);
        *(short8*)&WtH[l + 8] = *(const short8*)(Wfrag + g + 8);
        *(short8*)&WtL[l]     = *(const short8*)(Wfrag + 4096 + g);
        *(short8*)&WtL[l + 8] = *(const short8*)(Wfrag + 4096 + g + 8);
        *(short8*)&WwH[l]     = *(const short8*)(Wfrag + 8192 + g);
        *(short8*)&WwH[l + 8] = *(const short8*)(Wfrag + 8192 + g + 8);
        *(short8*)&WwL[l]     = *(const short8*)(Wfrag + 12288 + g);
        *(short8*)&WwL[l + 8] = *(const short8*)(Wfrag + 12288 + g + 8);
    }

    float inpC[4][4];
#pragma unroll
    for (int nt = 0; nt < 4; ++nt)
#pragma unroll
        for (int r = 0; r < 4; ++r)
            inpC[nt][r] = inp[(size_t)(rowbase + lq * 4 + r) * 64 + nt * 16 + lm];
    float r1c[4];
#pragma unroll
    for (int nt = 0; nt < 4; ++nt) r1c[nt] = r1inv[nt * 16 + lm];
    __syncthreads();   // W planes ready

    float hC[4][4], recC[4][4];
    {   // ---- iteration 1 (rec1 token-independent) ----
        float qC[4][4];
#pragma unroll
        for (int nt = 0; nt < 4; ++nt)
#pragma unroll
            for (int r = 0; r < 4; ++r) qC[nt][r] = inpC[nt][r] * r1c[nt];
        floatx4 u[4];
        mfma_matvec(qC, T, lm, lq, WwH, WwL, u);
#pragma unroll
        for (int nt = 0; nt < 4; ++nt)
#pragma unroll
            for (int r = 0; r < 4; ++r)
                hC[nt][r] = fmaxf(u[nt][r] * (1.f / 64.f), 1e-6f);
#pragma unroll
        for (int r = 0; r < 4; ++r) {
            float s = (hC[0][r] + hC[1][r]) + (hC[2][r] + hC[3][r]);
            s += __shfl_xor(s, 1, 64); s += __shfl_xor(s, 2, 64);
            s += __shfl_xor(s, 4, 64); s += __shfl_xor(s, 8, 64);
            const float inv = __builtin_amdgcn_rcpf(fmaxf(s, 1e-20f));
#pragma unroll
            for (int nt = 0; nt < 4; ++nt) hC[nt][r] *= inv;
        }
    }
#pragma unroll 1
    for (int it = 0; it < 2; ++it) {   // ---- iterations 2,3 (full) ----
        floatx4 t[4];
        mfma_matvec(hC, T, lm, lq, WtH, WtL, t);
        float tC[4][4], qC[4][4];
#pragma unroll
        for (int nt = 0; nt < 4; ++nt)
#pragma unroll
            for (int r = 0; r < 4; ++r) tC[nt][r] = fmaxf(t[nt][r], 1e-6f);
#pragma unroll
        for (int r = 0; r < 4; ++r) {
            float s = (tC[0][r] + tC[1][r]) + (tC[2][r] + tC[3][r]);
            s += __shfl_xor(s, 1, 64); s += __shfl_xor(s, 2, 64);
            s += __shfl_xor(s, 4, 64); s += __shfl_xor(s, 8, 64);
            s = fmaxf(s, 1e-20f);
            const float invS = __builtin_amdgcn_rcpf(s);
#pragma unroll
            for (int nt = 0; nt < 4; ++nt) {
                recC[nt][r] = tC[nt][r] * invS;
                qC[nt][r] = inpC[nt][r] * s * __builtin_amdgcn_rcpf(tC[nt][r]);
            }
        }
        floatx4 u[4];
        mfma_matvec(qC, T, lm, lq, WwH, WwL, u);
#pragma unroll
        for (int nt = 0; nt < 4; ++nt)
#pragma unroll
            for (int r = 0; r < 4; ++r)
                hC[nt][r] = fmaxf(hC[nt][r] * u[nt][r], 1e-6f);
#pragma unroll
        for (int r = 0; r < 4; ++r) {
            float s = (hC[0][r] + hC[1][r]) + (hC[2][r] + hC[3][r]);
            s += __shfl_xor(s, 1, 64); s += __shfl_xor(s, 2, 64);
            s += __shfl_xor(s, 4, 64); s += __shfl_xor(s, 8, 64);
            const float inv = __builtin_amdgcn_rcpf(fmaxf(s, 1e-20f));
#pragma unroll
            for (int nt = 0; nt < 4; ++nt) hC[nt][r] *= inv;
        }
    }
#pragma unroll
    for (int r = 0; r < 4; ++r) {   // normalize_h
        float s = (hC[0][r] + hC[1][r]) + (hC[2][r] + hC[3][r]);
        s += __shfl_xor(s, 1, 64); s += __shfl_xor(s, 2, 64);
        s += __shfl_xor(s, 4, 64); s += __shfl_xor(s, 8, 64);
        const float inv = __builtin_amdgcn_rcpf(fmaxf(s, 1e-20f));
#pragma unroll
        for (int nt = 0; nt < 4; ++nt) hC[nt][r] *= inv;
    }

    // stores: h, rec*inp row-major [o][f]
#pragma unroll
    for (int nt = 0; nt < 4; ++nt)
#pragma unroll
        for (int r = 0; r < 4; ++r) {
            const size_t o = (size_t)(rowbase + lq * 4 + r) * 64 + nt * 16 + lm;
            hout[o] = hC[nt][r];
            hriout[o] = recC[nt][r] * inpC[nt][r];
        }

    // per-block partial of sum_o h[o,f]: wave-reduce + LDS combine + plain store
    float hs[4];
#pragma unroll
    for (int nt = 0; nt < 4; ++nt) {
        float s = (hC[nt][0] + hC[nt][1]) + (hC[nt][2] + hC[nt][3]);
        s += __shfl_xor(s, 16, 64);
        s += __shfl_xor(s, 32, 64);
        hs[nt] = s;
    }
    pbuf[wv * 64 + lq * 16 + lm] = hs[lq];
    __syncthreads();
    if (tid < 64) {
        float tot = (pbuf[tid] + pbuf[64 + tid]) + (pbuf[128 + tid] + pbuf[192 + tid]);
        mp0[(size_t)blockIdx.x * 64 + tid] = tot;
    }
}

// ---------------------------------------------------------------------------
// K4: one alpha iteration per launch, 384 blocks = (bh) x (64-o chunk).
// All outputs are exclusive plain stores.
// ---------------------------------------------------------------------------
__global__ __launch_bounds__(256) void k_alpha_step(const float* __restrict__ hin,
                                                    const float* __restrict__ hri,
                                                    const float* __restrict__ Wn,
                                                    const float* __restrict__ mp_in,
                                                    float* __restrict__ mp_out,
                                                    float* __restrict__ c,
                                                    int it) {
    __shared__ float mred[4][64];
    __shared__ float mv[64];
    __shared__ float vv[64];
    __shared__ float cl[64];
    const int tid = threadIdx.x;
    const int bh = blockIdx.x >> 4;
    const int chunk = blockIdx.x & 15;
    const size_t rowbase = (size_t)bh * 1024 + chunk * 64;

    {
        int f = tid & 63, p = tid >> 6;
        float s = 0.f;
#pragma unroll
        for (int pp = 0; pp < 4; ++pp)
            s += mp_in[((size_t)bh * 16 + p * 4 + pp) * 64 + f];
        mred[p][f] = s;
    }
    __syncthreads();
    if (tid < 64)
        mv[tid] = (mred[0][tid] + mred[1][tid]) + (mred[2][tid] + mred[3][tid]);
    __syncthreads();
    {
        int d = tid & 63, qq = tid >> 6;
        float r = 0.f;
#pragma unroll
        for (int ff = 0; ff < 16; ++ff)
            r = fmaf(mv[qq * 16 + ff], Wn[(size_t)(qq * 16 + ff) * 64 + d], r);
        mred[qq][d] = r;
    }
    __syncthreads();
    if (tid < 64)
        vv[tid] = 1.f / (((mred[0][tid] + mred[1][tid]) + (mred[2][tid] + mred[3][tid])) + 1e-20f);
    __syncthreads();
    {
        int o = tid >> 2, dq = tid & 3;
        const float* rp = hri + (rowbase + o) * 64 + dq * 16;
        float dot = 0.f;
#pragma unroll
        for (int t4 = 0; t4 < 16; t4 += 4) {
            float4 r4 = *(const float4*)(rp + t4);
            dot = fmaf(r4.x, vv[dq * 16 + t4 + 0], dot);
            dot = fmaf(r4.y, vv[dq * 16 + t4 + 1], dot);
            dot = fmaf(r4.z, vv[dq * 16 + t4 + 2], dot);
            dot = fmaf(r4.w, vv[dq * 16 + t4 + 3], dot);
        }
        dot += __shfl_xor(dot, 1, 64);
        dot += __shfl_xor(dot, 2, 64);
        float cn = dot;
        if (it >= 2) cn *= c[rowbase + o];
        if (dq == 0) { c[rowbase + o] = cn; cl[o] = cn; }
    }
    __syncthreads();
    {
        const int f4 = (tid & 15) * 4, ogr = tid >> 4;
        float4 a = make_float4(0.f, 0.f, 0.f, 0.f);
#pragma unroll
        for (int oi = 0; oi < 4; ++oi) {
            int o = ogr * 4 + oi;
            float4 h4 = *(const float4*)(hin + (rowbase + o) * 64 + f4);
            float cv = cl[o];
            a.x = fmaf(h4.x, cv, a.x); a.y = fmaf(h4.y, cv, a.y);
            a.z = fmaf(h4.z, cv, a.z); a.w = fmaf(h4.w, cv, a.w);
        }
        a.x += __shfl_xor(a.x, 16, 64); a.y += __shfl_xor(a.y, 16, 64);
        a.z += __shfl_xor(a.z, 16, 64); a.w += __shfl_xor(a.w, 16, 64);
        a.x += __shfl_xor(a.x, 32, 64); a.y += __shfl_xor(a.y, 32, 64);
        a.z += __shfl_xor(a.z, 32, 64); a.w += __shfl_xor(a.w, 32, 64);
        const int w = tid >> 6;
        if ((tid & 63) < 16) *(float4*)&mred[w][(tid & 15) * 4] = a;
    }
    __syncthreads();
    if (tid < 64) {
        float s = (mred[0][tid] + mred[1][tid]) + (mred[2][tid] + mred[3][tid]);
        mp_out[((size_t)bh * 16 + chunk) * 64 + tid] = s;
    }
}

// ---------------------------------------------------------------------------
// K5: out-projection + broadcast, 384 blocks = (b) x (12 out-seg) x (16 rowgrp).
// Folds the final 16-chunk M reduction into the Ml load.
// ---------------------------------------------------------------------------
__global__ __launch_bounds__(256) void k_projbcast(const float* __restrict__ mp3,
                                                   const float* __restrict__ ow,
                                                   const float* __restrict__ ob,
                                                   float* __restrict__ out) {
    __shared__ float Ml[768];
    __shared__ float ps[4][64];
    __shared__ float yseg[64];
    const int tid = threadIdx.x;
    const int b = blockIdx.x / 192;
    const int rem = blockIdx.x - b * 192;
    const int jt = rem >> 4, rg = rem & 15;
    for (int i = tid; i < 768; i += 256) {
        const int hh = i >> 6, f = i & 63;
        const float* src = mp3 + ((size_t)(b * 12 + hh) * 16) * 64 + f;
        float s = 0.f;
#pragma unroll
        for (int cc = 0; cc < 16; ++cc) s += src[cc * 64];
        Ml[i] = s;
    }
    __syncthreads();
    const int jj = tid & 63, part = tid >> 6;
    const int j = jt * 64 + jj;
    const float* row = ow + (size_t)j * 768 + part * 192;
    float acc = 0.f;
    for (int t = 0; t < 192; t += 4) {
        float4 w4 = *(const float4*)(row + t);
        acc = fmaf(w4.x, Ml[part * 192 + t + 0], acc);
        acc = fmaf(w4.y, Ml[part * 192 + t + 1], acc);
        acc = fmaf(w4.z, Ml[part * 192 + t + 2], acc);
        acc = fmaf(w4.w, Ml[part * 192 + t + 3], acc);
    }
    ps[part][jj] = acc;
    __syncthreads();
    if (tid < 64)
        yseg[tid] = ps[0][tid] + ps[1][tid] + ps[2][tid] + ps[3][tid] + ob[jt * 64 + tid];
    __syncthreads();
    const int r0 = tid >> 2, c4 = (tid & 3) * 16;
    float4 v4[4];
#pragma unroll
    for (int q = 0; q < 4; ++q) v4[q] = *(const float4*)&yseg[c4 + q * 4];
    float* dst = out + ((size_t)(b * 1024 + rg * 64 + r0)) * 768 + jt * 64 + c4;
#pragma unroll
    for (int q = 0; q < 4; ++q) *(float4*)(dst + q * 4) = v4[q];
}

extern "C" void kernel_launch(void* const* d_in, const int* in_sizes, int n_in,
                              void* d_out, int out_size, void* d_ws, size_t ws_size,
                              hipStream_t stream) {
    const float* xs = (const float*)d_in[0];  // [2,1024,768]
    const float* ew = (const float*)d_in[1];  // [768,768]
    const float* eb = (const float*)d_in[2];  // [768]
    const float* nw = (const float*)d_in[3];  // [64,64]
    const float* ow = (const float*)d_in[4];  // [768,768]
    const float* ob = (const float*)d_in[5];  // [768]
    float* out = (float*)d_out;               // [2,1024,768]

    float* ws    = (float*)d_ws;
    float* inp   = ws;                     // 1572864 f
    float* h     = ws + 1572864;           // 1572864 f
    float* hri   = ws + 3145728;           // 1572864 f
    float* Wn    = ws + 4718592;           // 4096 f
    float* r1inv = ws + 4722688;           // 256 f
    float* mp0   = ws + 4722944;           // 24576 f
    float* mp1   = ws + 4747520;           // 24576 f
    float* mp2   = ws + 4772096;           // 24576 f
    float* c     = ws + 4796672;           // 24576 f
    ushort* xsH  = (ushort*)(ws + 4821248);    // 1572864 us (786432 f)
    ushort* xsL  = (ushort*)(ws + 5607680);    // 1572864 us
    ushort* ewH  = (ushort*)(ws + 6394112);    // 589824 us (294912 f)
    ushort* ewL  = (ushort*)(ws + 6689024);    // 589824 us
    ushort* Wfrag= (ushort*)(ws + 6983936);    // 16384 us (8192 f)

    k_conv<<<1057, 256, 0, stream>>>(xs, ew, nw, xsH, xsL, ewH, ewL, Wn, r1inv, Wfrag);
    k_embed<<<768, 256, 0, stream>>>(xsH, xsL, ewH, ewL, eb, inp);
    k_nnmf<<<384, 256, 0, stream>>>(inp, Wfrag, r1inv, h, hri, mp0);
    k_alpha_step<<<384, 256, 0, stream>>>(h, hri, Wn, mp0, mp1, c, 1);
    k_alpha_step<<<384, 256, 0, stream>>>(h, hri, Wn, mp1, mp2, c, 2);
    k_alpha_step<<<384, 256, 0, stream>>>(h, hri, Wn, mp2, mp1, c, 3);
    k_projbcast<<<384, 256, 0, stream>>>(mp1, ow, ob, out);
}

// Round 8
// 132.997 us; speedup vs baseline: 1.2389x; 1.2389x over previous
//
#include <hip/hip_runtime.h>

// Problem constants
#define B_  2
#define S_  1024
#define FIN 768
#define E_  768
#define H_  12
#define DH  64   // = FH = 64

typedef unsigned int uint;
typedef unsigned short ushort;
typedef __attribute__((ext_vector_type(8))) short short8;    // 8 bf16 (4 VGPRs)
typedef __attribute__((ext_vector_type(4))) float floatx4;   // MFMA acc

__device__ __forceinline__ ushort f2bf(float f) {   // RNE float->bf16 bits
    uint u = __float_as_uint(f);
    return (ushort)((u + 0x7fffu + ((u >> 16) & 1u)) >> 16);
}

__device__ __forceinline__ uint4 pack8(const ushort* p) {
    uint4 r;
    r.x = (uint)p[0] | ((uint)p[1] << 16);
    r.y = (uint)p[2] | ((uint)p[3] << 16);
    r.z = (uint)p[4] | ((uint)p[5] << 16);
    r.w = (uint)p[6] | ((uint)p[7] << 16);
    return r;
}

__device__ __forceinline__ void split8v(float4 a, float4 b, short8& hi, short8& lo) {
    float v[8] = {a.x, a.y, a.z, a.w, b.x, b.y, b.z, b.w};
    ushort h[8], l[8];
#pragma unroll
    for (int j = 0; j < 8; ++j) {
        h[j] = f2bf(v[j]);
        l[j] = f2bf(v[j] - __uint_as_float(((uint)h[j]) << 16));
    }
    uint4 H = pack8(h), L = pack8(l);
    hi = *(short8*)&H;
    lo = *(short8*)&L;
}

// ---------------------------------------------------------------------------
// K0: conversion + prep pass. blocks 0..767: xs -> xsH/xsL bf16 split planes.
// blocks 768..1055: ew -> ewH/ewL. block 1056: W-prep (Wn, r1inv, Wfrag).
// ---------------------------------------------------------------------------
__global__ __launch_bounds__(256) void k_conv(const float* __restrict__ xs,
                                              const float* __restrict__ ew,
                                              const float* __restrict__ nw,
                                              ushort* __restrict__ xsH,
                                              ushort* __restrict__ xsL,
                                              ushort* __restrict__ ewH,
                                              ushort* __restrict__ ewL,
                                              float* __restrict__ Wn,
                                              float* __restrict__ r1inv,
                                              ushort* __restrict__ Wfrag) {
    __shared__ float Wl[64 * 65];
    const int tid = threadIdx.x, bid = blockIdx.x;

    if (bid < 768) {          // xs conversion: 2048x768 / 8 per thread
        const size_t i = ((size_t)bid * 256 + tid) * 8;
        short8 hi, lo;
        split8v(*(const float4*)(xs + i), *(const float4*)(xs + i + 4), hi, lo);
        *(short8*)(xsH + i) = hi;
        *(short8*)(xsL + i) = lo;
        return;
    }
    if (bid < 1056) {         // ew conversion: 768x768 / 8 per thread
        const size_t i = ((size_t)(bid - 768) * 256 + tid) * 8;
        short8 hi, lo;
        split8v(*(const float4*)(ew + i), *(const float4*)(ew + i + 4), hi, lo);
        *(short8*)(ewH + i) = hi;
        *(short8*)(ewL + i) = lo;
        return;
    }

    // ---- prep block (bid == 1056) ----
    const int f = tid >> 2, q = tid & 3;
    float v[16];
    float s = 0.f;
#pragma unroll
    for (int i = 0; i < 16; ++i) { v[i] = nw[f * 64 + q * 16 + i]; s += v[i]; }
    s += __shfl_xor(s, 1, 64);
    s += __shfl_xor(s, 2, 64);
    const float inv = 1.f / fmaxf(s, 1e-20f);
    float w[16];
#pragma unroll
    for (int i = 0; i < 16; ++i) {
        w[i] = v[i] * inv;
        Wn[f * 64 + q * 16 + i] = w[i];
        Wl[f * 65 + q * 16 + i] = w[i];
    }
    __syncthreads();
    if (tid < 64) {
        float cs = 0.f;
        for (int ff = 0; ff < 64; ++ff) cs += Wl[ff * 65 + tid];
        float t = fmaxf(cs * (1.f / 64.f), 1e-6f);
        float S = t;
#pragma unroll
        for (int m = 1; m < 64; m <<= 1) S += __shfl_xor(S, m, 64);
        S = fmaxf(S, 1e-20f);
        r1inv[tid] = S / t;   // 1/rec1
    }
    // Ww planes (rows of Wn) from registers: row f, quarter q
    {
        short8 h0, l0, h1, l1;
        split8v(make_float4(w[0], w[1], w[2], w[3]),
                make_float4(w[4], w[5], w[6], w[7]), h0, l0);
        split8v(make_float4(w[8], w[9], w[10], w[11]),
                make_float4(w[12], w[13], w[14], w[15]), h1, l1);
        ushort* WwH = Wfrag + 2 * 4096;
        ushort* WwL = Wfrag + 3 * 4096;
        *(short8*)(WwH + f * 64 + q * 16) = h0;
        *(short8*)(WwH + f * 64 + q * 16 + 8) = h1;
        *(short8*)(WwL + f * 64 + q * 16) = l0;
        *(short8*)(WwL + f * 64 + q * 16 + 8) = l1;
    }
    // Wt planes (rows of WnT) from LDS: WnT[f][q*16+i] = Wn[q*16+i][f]
    {
        float t[16];
#pragma unroll
        for (int i = 0; i < 16; ++i) t[i] = Wl[(q * 16 + i) * 65 + f];
        short8 h0, l0, h1, l1;
        split8v(make_float4(t[0], t[1], t[2], t[3]),
                make_float4(t[4], t[5], t[6], t[7]), h0, l0);
        split8v(make_float4(t[8], t[9], t[10], t[11]),
                make_float4(t[12], t[13], t[14], t[15]), h1, l1);
        ushort* WtH = Wfrag;
        ushort* WtL = Wfrag + 4096;
        *(short8*)(WtH + f * 64 + q * 16) = h0;
        *(short8*)(WtH + f * 64 + q * 16 + 8) = h1;
        *(short8*)(WtL + f * 64 + q * 16) = l0;
        *(short8*)(WtL + f * 64 + q * 16 + 8) = l1;
    }
}

// ---------------------------------------------------------------------------
// K1: MFMA embed, 384 blocks = (32 tok-grp of 64) x (12 heads); head-fastest
// for L2 x-reuse. Tile 64 tok x 64 out, 4 waves of 16 tok x 64 out each.
// LDS-staged (coalesced global reads, pure copy), 24 MFMA per wave per panel,
// per-token l1norm fully wave-internal (no cross-wave reduce).
// ---------------------------------------------------------------------------
__global__ __launch_bounds__(256) void k_embed(const ushort* __restrict__ xsH,
                                               const ushort* __restrict__ xsL,
                                               const ushort* __restrict__ ewH,
                                               const ushort* __restrict__ ewL,
                                               const float* __restrict__ eb,
                                               float* __restrict__ inp) {
    __shared__ ushort As_hi[64 * 72], As_lo[64 * 72];
    __shared__ ushort Bs_hi[64 * 72], Bs_lo[64 * 72];
    const int tid = threadIdx.x;
    const int bid = blockIdx.x;

    const int head = bid % 12;           // fastest -> consecutive blocks share x-tile
    const int tok0 = (bid / 12) * 64;

    const int wv = tid >> 6, lane = tid & 63;
    const int mbase = wv * 16;           // wave's 16-token rows
    const int lm = lane & 15, lq = lane >> 4;

    // accumulators: 4 n-tiles, dual chains (hi*hi vs cross terms)
    floatx4 accA[4], accB[4];
#pragma unroll
    for (int nt = 0; nt < 4; ++nt) { accA[nt] = (floatx4)0.f; accB[nt] = (floatx4)0.f; }

    // staging assignment: thread -> row tid>>2 (0..63), k-quarter (tid&3)*16
    const int srow = tid >> 2, skq = (tid & 3) * 16;
    const ushort* xh = xsH + (size_t)(tok0 + srow) * FIN + skq;
    const ushort* xl = xsL + (size_t)(tok0 + srow) * FIN + skq;
    const ushort* wh = ewH + (size_t)(head * 64 + srow) * FIN + skq;
    const ushort* wl = ewL + (size_t)(head * 64 + srow) * FIN + skq;

    short8 pa[4], pb[4];   // A hi0,hi1,lo0,lo1 / B hi0,hi1,lo0,lo1
    pa[0] = *(const short8*)(xh);     pa[1] = *(const short8*)(xh + 8);
    pa[2] = *(const short8*)(xl);     pa[3] = *(const short8*)(xl + 8);
    pb[0] = *(const short8*)(wh);     pb[1] = *(const short8*)(wh + 8);
    pb[2] = *(const short8*)(wl);     pb[3] = *(const short8*)(wl + 8);

    for (int kb = 0; kb < FIN; kb += 64) {
        __syncthreads();   // previous panel's frag reads done
        {
            const int off = srow * 72 + skq;
            *(short8*)&As_hi[off]     = pa[0];
            *(short8*)&As_hi[off + 8] = pa[1];
            *(short8*)&As_lo[off]     = pa[2];
            *(short8*)&As_lo[off + 8] = pa[3];
            *(short8*)&Bs_hi[off]     = pb[0];
            *(short8*)&Bs_hi[off + 8] = pb[1];
            *(short8*)&Bs_lo[off]     = pb[2];
            *(short8*)&Bs_lo[off + 8] = pb[3];
        }
        __syncthreads();
        if (kb + 64 < FIN) {   // prefetch next panel during compute
            const int ko = kb + 64;
            pa[0] = *(const short8*)(xh + ko);  pa[1] = *(const short8*)(xh + ko + 8);
            pa[2] = *(const short8*)(xl + ko);  pa[3] = *(const short8*)(xl + ko + 8);
            pb[0] = *(const short8*)(wh + ko);  pb[1] = *(const short8*)(wh + ko + 8);
            pb[2] = *(const short8*)(wl + ko);  pb[3] = *(const short8*)(wl + ko + 8);
        }
#pragma unroll
        for (int ch = 0; ch < 2; ++ch) {
            const int ko = ch * 32 + lq * 8;
            short8 ah = *(const short8*)&As_hi[(mbase + lm) * 72 + ko];
            short8 al = *(const short8*)&As_lo[(mbase + lm) * 72 + ko];
#pragma unroll
            for (int nt = 0; nt < 4; ++nt) {
                short8 bh = *(const short8*)&Bs_hi[(nt * 16 + lm) * 72 + ko];
                short8 bl = *(const short8*)&Bs_lo[(nt * 16 + lm) * 72 + ko];
                accA[nt] = __builtin_amdgcn_mfma_f32_16x16x32_bf16(ah, bh, accA[nt], 0, 0, 0);
                accB[nt] = __builtin_amdgcn_mfma_f32_16x16x32_bf16(al, bh, accB[nt], 0, 0, 0);
                accB[nt] = __builtin_amdgcn_mfma_f32_16x16x32_bf16(ah, bl, accB[nt], 0, 0, 0);
            }
        }
    }

    // epilogue: bias, clamp, per-token l1norm over 64 outs (wave-internal), store
    float bb[4];
#pragma unroll
    for (int nt = 0; nt < 4; ++nt) bb[nt] = eb[head * 64 + nt * 16 + lm];
    const size_t obase = ((size_t)((tok0 >> 10) * 12 + head) * 1024 + (tok0 & 1023));
#pragma unroll
    for (int r = 0; r < 4; ++r) {
        float e[4];
        float p = 0.f;
#pragma unroll
        for (int nt = 0; nt < 4; ++nt) {
            e[nt] = fmaxf((accA[nt][r] + accB[nt][r]) + bb[nt], 1e-6f);
            p += e[nt];
        }
        p += __shfl_xor(p, 1, 64);
        p += __shfl_xor(p, 2, 64);
        p += __shfl_xor(p, 4, 64);
        p += __shfl_xor(p, 8, 64);
        const float inv = 1.f / fmaxf(p, 1e-20f);
        const int m = mbase + lq * 4 + r;
        float* op = inp + (obase + m) * 64;
#pragma unroll
        for (int nt = 0; nt < 4; ++nt)
            op[nt * 16 + lm] = e[nt] * inv;
    }
}

// ---------------------------------------------------------------------------
// helper: 64x64 matvec via MFMA with split-bf16 B planes in LDS (wave-private T)
// dual accumulator chains for ILP.
// ---------------------------------------------------------------------------
__device__ __forceinline__ void mfma_matvec(const float srcC[4][4], float* T,
                                            int lm, int lq,
                                            const ushort* WH, const ushort* WL,
                                            floatx4 out[4]) {
    __builtin_amdgcn_wave_barrier();
#pragma unroll
    for (int nt = 0; nt < 4; ++nt)
#pragma unroll
        for (int r = 0; r < 4; ++r)
            T[(lq * 4 + r) * 68 + nt * 16 + lm] = srcC[nt][r];
    __builtin_amdgcn_wave_barrier();
    float4 a00 = *(const float4*)&T[lm * 68 + lq * 8];
    float4 a01 = *(const float4*)&T[lm * 68 + lq * 8 + 4];
    float4 a10 = *(const float4*)&T[lm * 68 + 32 + lq * 8];
    float4 a11 = *(const float4*)&T[lm * 68 + 32 + lq * 8 + 4];
    __builtin_amdgcn_wave_barrier();
    short8 A0h, A0l, A1h, A1l;
    split8v(a00, a01, A0h, A0l);
    split8v(a10, a11, A1h, A1l);
#pragma unroll
    for (int nt = 0; nt < 4; ++nt) {
        const int row = (nt * 16 + lm) * 72;
        short8 b0h = *(const short8*)&WH[row + lq * 8];
        short8 b0l = *(const short8*)&WL[row + lq * 8];
        short8 b1h = *(const short8*)&WH[row + 32 + lq * 8];
        short8 b1l = *(const short8*)&WL[row + 32 + lq * 8];
        floatx4 acc0 = (floatx4)0.f, acc1 = (floatx4)0.f;
        acc0 = __builtin_amdgcn_mfma_f32_16x16x32_bf16(A0h, b0h, acc0, 0, 0, 0);
        acc0 = __builtin_amdgcn_mfma_f32_16x16x32_bf16(A0l, b0h, acc0, 0, 0, 0);
        acc0 = __builtin_amdgcn_mfma_f32_16x16x32_bf16(A0h, b0l, acc0, 0, 0, 0);
        acc1 = __builtin_amdgcn_mfma_f32_16x16x32_bf16(A1h, b1h, acc1, 0, 0, 0);
        acc1 = __builtin_amdgcn_mfma_f32_16x16x32_bf16(A1l, b1h, acc1, 0, 0, 0);
        acc1 = __builtin_amdgcn_mfma_f32_16x16x32_bf16(A1h, b1l, acc1, 0, 0, 0);
        out[nt] = acc0 + acc1;
    }
}

// ---------------------------------------------------------------------------
// K3: NNMF updates, 16 tokens per wave, 384 blocks x 4 waves.
// W fragment planes are pre-built (k_conv) — staging is a pure copy.
// ---------------------------------------------------------------------------
__global__ __launch_bounds__(256) void k_nnmf(const float* __restrict__ inp,
                                              const ushort* __restrict__ Wfrag,
                                              const float* __restrict__ r1inv,
                                              float* __restrict__ hout,
                                              float* __restrict__ hriout,
                                              float* __restrict__ mp0) {
    __shared__ ushort WtH[64 * 72], WtL[64 * 72];
    __shared__ ushort WwH[64 * 72], WwL[64 * 72];
    __shared__ float Tb[4][16 * 68];
    __shared__ float pbuf[256];
    const int tid = threadIdx.x, wv = tid >> 6, lane = tid & 63;
    const int lm = lane & 15, lq = lane >> 4;
    float* T = Tb[wv];
    const int rowbase = blockIdx.x * 64 + wv * 16;

    {   // stage W planes: pure copy, thread -> row tid>>2, k-quarter (tid&3)*16
        const int row = tid >> 2, kq = (tid & 3) * 16;
        const int g = row * 64 + kq, l = row * 72 + kq;
        *(short8*)&WtH[l]     = *(const short8*)(Wfrag + g);
        *(short8*)&WtH[l + 8] = *(const short8*)(Wfrag + g + 8);
        *(short8*)&WtL[l]     = *(const short8*)(Wfrag + 4096 + g);
        *(short8*)&WtL[l + 8] = *(const short8*)(Wfrag + 4096 + g + 8);
        *(short8*)&WwH[l]     = *(const short8*)(Wfrag + 8192 + g);
        *(short8*)&WwH[l + 8] = *(const short8*)(Wfrag + 8192 + g + 8);
        *(short8*)&WwL[l]     = *(const short8*)(Wfrag + 12288 + g);
        *(short8*)&WwL[l + 8] = *(const short8*)(Wfrag + 12288 + g + 8);
    }

    float inpC[4][4];
#pragma unroll
    for (int nt = 0; nt < 4; ++nt)
#pragma unroll
        for (int r = 0; r < 4; ++r)
            inpC[nt][r] = inp[(size_t)(rowbase + lq * 4 + r) * 64 + nt * 16 + lm];
    float r1c[4];
#pragma unroll
    for (int nt = 0; nt < 4; ++nt) r1c[nt] = r1inv[nt * 16 + lm];
    __syncthreads();   // W planes ready

    float hC[4][4], recC[4][4];
    {   // ---- iteration 1 (rec1 token-independent) ----
        float qC[4][4];
#pragma unroll
        for (int nt = 0; nt < 4; ++nt)
#pragma unroll
            for (int r = 0; r < 4; ++r) qC[nt][r] = inpC[nt][r] * r1c[nt];
        floatx4 u[4];
        mfma_matvec(qC, T, lm, lq, WwH, WwL, u);
#pragma unroll
        for (int nt = 0; nt < 4; ++nt)
#pragma unroll
            for (int r = 0; r < 4; ++r)
                hC[nt][r] = fmaxf(u[nt][r] * (1.f / 64.f), 1e-6f);
#pragma unroll
        for (int r = 0; r < 4; ++r) {
            float s = (hC[0][r] + hC[1][r]) + (hC[2][r] + hC[3][r]);
            s += __shfl_xor(s, 1, 64); s += __shfl_xor(s, 2, 64);
            s += __shfl_xor(s, 4, 64); s += __shfl_xor(s, 8, 64);
            const float inv = __builtin_amdgcn_rcpf(fmaxf(s, 1e-20f));
#pragma unroll
            for (int nt = 0; nt < 4; ++nt) hC[nt][r] *= inv;
        }
    }
#pragma unroll 1
    for (int it = 0; it < 2; ++it) {   // ---- iterations 2,3 (full) ----
        floatx4 t[4];
        mfma_matvec(hC, T, lm, lq, WtH, WtL, t);
        float tC[4][4], qC[4][4];
#pragma unroll
        for (int nt = 0; nt < 4; ++nt)
#pragma unroll
            for (int r = 0; r < 4; ++r) tC[nt][r] = fmaxf(t[nt][r], 1e-6f);
#pragma unroll
        for (int r = 0; r < 4; ++r) {
            float s = (tC[0][r] + tC[1][r]) + (tC[2][r] + tC[3][r]);
            s += __shfl_xor(s, 1, 64); s += __shfl_xor(s, 2, 64);
            s += __shfl_xor(s, 4, 64); s += __shfl_xor(s, 8, 64);
            s = fmaxf(s, 1e-20f);
            const float invS = __builtin_amdgcn_rcpf(s);
#pragma unroll
            for (int nt = 0; nt < 4; ++nt) {
                recC[nt][r] = tC[nt][r] * invS;
                qC[nt][r] = inpC[nt][r] * s * __builtin_amdgcn_rcpf(tC[nt][r]);
            }
        }
        floatx4 u[4];
        mfma_matvec(qC, T, lm, lq, WwH, WwL, u);
#pragma unroll
        for (int nt = 0; nt < 4; ++nt)
#pragma unroll
            for (int r = 0; r < 4; ++r)
                hC[nt][r] = fmaxf(hC[nt][r] * u[nt][r], 1e-6f);
#pragma unroll
        for (int r = 0; r < 4; ++r) {
            float s = (hC[0][r] + hC[1][r]) + (hC[2][r] + hC[3][r]);
            s += __shfl_xor(s, 1, 64); s += __shfl_xor(s, 2, 64);
            s += __shfl_xor(s, 4, 64); s += __shfl_xor(s, 8, 64);
            const float inv = __builtin_amdgcn_rcpf(fmaxf(s, 1e-20f));
#pragma unroll
            for (int nt = 0; nt < 4; ++nt) hC[nt][r] *= inv;
        }
    }
#pragma unroll
    for (int r = 0; r < 4; ++r) {   // normalize_h
        float s = (hC[0][r] + hC[1][r]) + (hC[2][r] + hC[3][r]);
        s += __shfl_xor(s, 1, 64); s += __shfl_xor(s, 2, 64);
        s += __shfl_xor(s, 4, 64); s += __shfl_xor(s, 8, 64);
        const float inv = __builtin_amdgcn_rcpf(fmaxf(s, 1e-20f));
#pragma unroll
        for (int nt = 0; nt < 4; ++nt) hC[nt][r] *= inv;
    }

    // stores: h, rec*inp row-major [o][f]
#pragma unroll
    for (int nt = 0; nt < 4; ++nt)
#pragma unroll
        for (int r = 0; r < 4; ++r) {
            const size_t o = (size_t)(rowbase + lq * 4 + r) * 64 + nt * 16 + lm;
            hout[o] = hC[nt][r];
            hriout[o] = recC[nt][r] * inpC[nt][r];
        }

    // per-block partial of sum_o h[o,f]: wave-reduce + LDS combine + plain store
    float hs[4];
#pragma unroll
    for (int nt = 0; nt < 4; ++nt) {
        float s = (hC[nt][0] + hC[nt][1]) + (hC[nt][2] + hC[nt][3]);
        s += __shfl_xor(s, 16, 64);
        s += __shfl_xor(s, 32, 64);
        hs[nt] = s;
    }
    pbuf[wv * 64 + lq * 16 + lm] = hs[lq];
    __syncthreads();
    if (tid < 64) {
        float tot = (pbuf[tid] + pbuf[64 + tid]) + (pbuf[128 + tid] + pbuf[192 + tid]);
        mp0[(size_t)blockIdx.x * 64 + tid] = tot;
    }
}

// ---------------------------------------------------------------------------
// K4: one alpha iteration per launch, 384 blocks = (bh) x (64-o chunk).
// All outputs are exclusive plain stores.
// ---------------------------------------------------------------------------
__global__ __launch_bounds__(256) void k_alpha_step(const float* __restrict__ hin,
                                                    const float* __restrict__ hri,
                                                    const float* __restrict__ Wn,
                                                    const float* __restrict__ mp_in,
                                                    float* __restrict__ mp_out,
                                                    float* __restrict__ c,
                                                    int it) {
    __shared__ float mred[4][64];
    __shared__ float mv[64];
    __shared__ float vv[64];
    __shared__ float cl[64];
    const int tid = threadIdx.x;
    const int bh = blockIdx.x >> 4;
    const int chunk = blockIdx.x & 15;
    const size_t rowbase = (size_t)bh * 1024 + chunk * 64;

    {
        int f = tid & 63, p = tid >> 6;
        float s = 0.f;
#pragma unroll
        for (int pp = 0; pp < 4; ++pp)
            s += mp_in[((size_t)bh * 16 + p * 4 + pp) * 64 + f];
        mred[p][f] = s;
    }
    __syncthreads();
    if (tid < 64)
        mv[tid] = (mred[0][tid] + mred[1][tid]) + (mred[2][tid] + mred[3][tid]);
    __syncthreads();
    {
        int d = tid & 63, qq = tid >> 6;
        float r = 0.f;
#pragma unroll
        for (int ff = 0; ff < 16; ++ff)
            r = fmaf(mv[qq * 16 + ff], Wn[(size_t)(qq * 16 + ff) * 64 + d], r);
        mred[qq][d] = r;
    }
    __syncthreads();
    if (tid < 64)
        vv[tid] = 1.f / (((mred[0][tid] + mred[1][tid]) + (mred[2][tid] + mred[3][tid])) + 1e-20f);
    __syncthreads();
    {
        int o = tid >> 2, dq = tid & 3;
        const float* rp = hri + (rowbase + o) * 64 + dq * 16;
        float dot = 0.f;
#pragma unroll
        for (int t4 = 0; t4 < 16; t4 += 4) {
            float4 r4 = *(const float4*)(rp + t4);
            dot = fmaf(r4.x, vv[dq * 16 + t4 + 0], dot);
            dot = fmaf(r4.y, vv[dq * 16 + t4 + 1], dot);
            dot = fmaf(r4.z, vv[dq * 16 + t4 + 2], dot);
            dot = fmaf(r4.w, vv[dq * 16 + t4 + 3], dot);
        }
        dot += __shfl_xor(dot, 1, 64);
        dot += __shfl_xor(dot, 2, 64);
        float cn = dot;
        if (it >= 2) cn *= c[rowbase + o];
        if (dq == 0) { c[rowbase + o] = cn; cl[o] = cn; }
    }
    __syncthreads();
    {
        const int f4 = (tid & 15) * 4, ogr = tid >> 4;
        float4 a = make_float4(0.f, 0.f, 0.f, 0.f);
#pragma unroll
        for (int oi = 0; oi < 4; ++oi) {
            int o = ogr * 4 + oi;
            float4 h4 = *(const float4*)(hin + (rowbase + o) * 64 + f4);
            float cv = cl[o];
            a.x = fmaf(h4.x, cv, a.x); a.y = fmaf(h4.y, cv, a.y);
            a.z = fmaf(h4.z, cv, a.z); a.w = fmaf(h4.w, cv, a.w);
        }
        a.x += __shfl_xor(a.x, 16, 64); a.y += __shfl_xor(a.y, 16, 64);
        a.z += __shfl_xor(a.z, 16, 64); a.w += __shfl_xor(a.w, 16, 64);
        a.x += __shfl_xor(a.x, 32, 64); a.y += __shfl_xor(a.y, 32, 64);
        a.z += __shfl_xor(a.z, 32, 64); a.w += __shfl_xor(a.w, 32, 64);
        const int w = tid >> 6;
        if ((tid & 63) < 16) *(float4*)&mred[w][(tid & 15) * 4] = a;
    }
    __syncthreads();
    if (tid < 64) {
        float s = (mred[0][tid] + mred[1][tid]) + (mred[2][tid] + mred[3][tid]);
        mp_out[((size_t)bh * 16 + chunk) * 64 + tid] = s;
    }
}

// ---------------------------------------------------------------------------
// K5: out-projection + broadcast, 384 blocks = (b) x (12 out-seg) x (16 rowgrp).
// Folds the final 16-chunk M reduction into the Ml load.
// ---------------------------------------------------------------------------
__global__ __launch_bounds__(256) void k_projbcast(const float* __restrict__ mp3,
                                                   const float* __restrict__ ow,
                                                   const float* __restrict__ ob,
                                                   float* __restrict__ out) {
    __shared__ float Ml[768];
    __shared__ float ps[4][64];
    __shared__ float yseg[64];
    const int tid = threadIdx.x;
    const int b = blockIdx.x / 192;
    const int rem = blockIdx.x - b * 192;
    const int jt = rem >> 4, rg = rem & 15;
    for (int i = tid; i < 768; i += 256) {
        const int hh = i >> 6, f = i & 63;
        const float* src = mp3 + ((size_t)(b * 12 + hh) * 16) * 64 + f;
        float s = 0.f;
#pragma unroll
        for (int cc = 0; cc < 16; ++cc) s += src[cc * 64];
        Ml[i] = s;
    }
    __syncthreads();
    const int jj = tid & 63, part = tid >> 6;
    const int j = jt * 64 + jj;
    const float* row = ow + (size_t)j * 768 + part * 192;
    float acc = 0.f;
    for (int t = 0; t < 192; t += 4) {
        float4 w4 = *(const float4*)(row + t);
        acc = fmaf(w4.x, Ml[part * 192 + t + 0], acc);
        acc = fmaf(w4.y, Ml[part * 192 + t + 1], acc);
        acc = fmaf(w4.z, Ml[part * 192 + t + 2], acc);
        acc = fmaf(w4.w, Ml[part * 192 + t + 3], acc);
    }
    ps[part][jj] = acc;
    __syncthreads();
    if (tid < 64)
        yseg[tid] = ps[0][tid] + ps[1][tid] + ps[2][tid] + ps[3][tid] + ob[jt * 64 + tid];
    __syncthreads();
    const int r0 = tid >> 2, c4 = (tid & 3) * 16;
    float4 v4[4];
#pragma unroll
    for (int q = 0; q < 4; ++q) v4[q] = *(const float4*)&yseg[c4 + q * 4];
    float* dst = out + ((size_t)(b * 1024 + rg * 64 + r0)) * 768 + jt * 64 + c4;
#pragma unroll
    for (int q = 0; q < 4; ++q) *(float4*)(dst + q * 4) = v4[q];
}

extern "C" void kernel_launch(void* const* d_in, const int* in_sizes, int n_in,
                              void* d_out, int out_size, void* d_ws, size_t ws_size,
                              hipStream_t stream) {
    const float* xs = (const float*)d_in[0];  // [2,1024,768]
    const float* ew = (const float*)d_in[1];  // [768,768]
    const float* eb = (const float*)d_in[2];  // [768]
    const float* nw = (const float*)d_in[3];  // [64,64]
    const float* ow = (const float*)d_in[4];  // [768,768]
    const float* ob = (const float*)d_in[5];  // [768]
    float* out = (float*)d_out;               // [2,1024,768]

    float* ws    = (float*)d_ws;
    float* inp   = ws;                     // 1572864 f
    float* h     = ws + 1572864;           // 1572864 f
    float* hri   = ws + 3145728;           // 1572864 f
    float* Wn    = ws + 4718592;           // 4096 f
    float* r1inv = ws + 4722688;           // 256 f
    float* mp0   = ws + 4722944;           // 24576 f
    float* mp1   = ws + 4747520;           // 24576 f
    float* mp2   = ws + 4772096;           // 24576 f
    float* c     = ws + 4796672;           // 24576 f
    ushort* xsH  = (ushort*)(ws + 4821248);    // 1572864 us (786432 f)
    ushort* xsL  = (ushort*)(ws + 5607680);    // 1572864 us
    ushort* ewH  = (ushort*)(ws + 6394112);    // 589824 us (294912 f)
    ushort* ewL  = (ushort*)(ws + 6689024);    // 589824 us
    ushort* Wfrag= (ushort*)(ws + 6983936);    // 16384 us (8192 f)

    k_conv<<<1057, 256, 0, stream>>>(xs, ew, nw, xsH, xsL, ewH, ewL, Wn, r1inv, Wfrag);
    k_embed<<<384, 256, 0, stream>>>(xsH, xsL, ewH, ewL, eb, inp);
    k_nnmf<<<384, 256, 0, stream>>>(inp, Wfrag, r1inv, h, hri, mp0);
    k_alpha_step<<<384, 256, 0, stream>>>(h, hri, Wn, mp0, mp1, c, 1);
    k_alpha_step<<<384, 256, 0, stream>>>(h, hri, Wn, mp1, mp2, c, 2);
    k_alpha_step<<<384, 256, 0, stream>>>(h, hri, Wn, mp2, mp1, c, 3);
    k_projbcast<<<384, 256, 0, stream>>>(mp1, ow, ob, out);
}

// Round 9
// 131.498 us; speedup vs baseline: 1.2531x; 1.0114x over previous
//
#include <hip/hip_runtime.h>

// Problem constants
#define B_  2
#define S_  1024
#define FIN 768
#define E_  768
#define H_  12
#define DH  64   // = FH = 64

typedef unsigned int uint;
typedef unsigned short ushort;
typedef __attribute__((ext_vector_type(8))) short short8;    // 8 bf16 (4 VGPRs)
typedef __attribute__((ext_vector_type(4))) float floatx4;   // MFMA acc

__device__ __forceinline__ ushort f2bf(float f) {   // RNE float->bf16 bits
    uint u = __float_as_uint(f);
    return (ushort)((u + 0x7fffu + ((u >> 16) & 1u)) >> 16);
}

__device__ __forceinline__ uint4 pack8(const ushort* p) {
    uint4 r;
    r.x = (uint)p[0] | ((uint)p[1] << 16);
    r.y = (uint)p[2] | ((uint)p[3] << 16);
    r.z = (uint)p[4] | ((uint)p[5] << 16);
    r.w = (uint)p[6] | ((uint)p[7] << 16);
    return r;
}

__device__ __forceinline__ void split8v(float4 a, float4 b, short8& hi, short8& lo) {
    float v[8] = {a.x, a.y, a.z, a.w, b.x, b.y, b.z, b.w};
    ushort h[8], l[8];
#pragma unroll
    for (int j = 0; j < 8; ++j) {
        h[j] = f2bf(v[j]);
        l[j] = f2bf(v[j] - __uint_as_float(((uint)h[j]) << 16));
    }
    uint4 H = pack8(h), L = pack8(l);
    hi = *(short8*)&H;
    lo = *(short8*)&L;
}

// ---------------------------------------------------------------------------
// K0: conversion + prep pass. blocks 0..767: xs -> xsH/xsL bf16 split planes.
// blocks 768..1055: ew -> ewH/ewL. block 1056: W-prep (Wn, r1inv, Wfrag).
// ---------------------------------------------------------------------------
__global__ __launch_bounds__(256) void k_conv(const float* __restrict__ xs,
                                              const float* __restrict__ ew,
                                              const float* __restrict__ nw,
                                              ushort* __restrict__ xsH,
                                              ushort* __restrict__ xsL,
                                              ushort* __restrict__ ewH,
                                              ushort* __restrict__ ewL,
                                              float* __restrict__ Wn,
                                              float* __restrict__ r1inv,
                                              ushort* __restrict__ Wfrag) {
    __shared__ float Wl[64 * 65];
    const int tid = threadIdx.x, bid = blockIdx.x;

    if (bid < 768) {          // xs conversion: 2048x768 / 8 per thread
        const size_t i = ((size_t)bid * 256 + tid) * 8;
        short8 hi, lo;
        split8v(*(const float4*)(xs + i), *(const float4*)(xs + i + 4), hi, lo);
        *(short8*)(xsH + i) = hi;
        *(short8*)(xsL + i) = lo;
        return;
    }
    if (bid < 1056) {         // ew conversion: 768x768 / 8 per thread
        const size_t i = ((size_t)(bid - 768) * 256 + tid) * 8;
        short8 hi, lo;
        split8v(*(const float4*)(ew + i), *(const float4*)(ew + i + 4), hi, lo);
        *(short8*)(ewH + i) = hi;
        *(short8*)(ewL + i) = lo;
        return;
    }

    // ---- prep block (bid == 1056) ----
    const int f = tid >> 2, q = tid & 3;
    float v[16];
    float s = 0.f;
#pragma unroll
    for (int i = 0; i < 16; ++i) { v[i] = nw[f * 64 + q * 16 + i]; s += v[i]; }
    s += __shfl_xor(s, 1, 64);
    s += __shfl_xor(s, 2, 64);
    const float inv = 1.f / fmaxf(s, 1e-20f);
    float w[16];
#pragma unroll
    for (int i = 0; i < 16; ++i) {
        w[i] = v[i] * inv;
        Wn[f * 64 + q * 16 + i] = w[i];
        Wl[f * 65 + q * 16 + i] = w[i];
    }
    __syncthreads();
    if (tid < 64) {
        float cs = 0.f;
        for (int ff = 0; ff < 64; ++ff) cs += Wl[ff * 65 + tid];
        float t = fmaxf(cs * (1.f / 64.f), 1e-6f);
        float S = t;
#pragma unroll
        for (int m = 1; m < 64; m <<= 1) S += __shfl_xor(S, m, 64);
        S = fmaxf(S, 1e-20f);
        r1inv[tid] = S / t;   // 1/rec1
    }
    // Ww planes (rows of Wn) from registers: row f, quarter q
    {
        short8 h0, l0, h1, l1;
        split8v(make_float4(w[0], w[1], w[2], w[3]),
                make_float4(w[4], w[5], w[6], w[7]), h0, l0);
        split8v(make_float4(w[8], w[9], w[10], w[11]),
                make_float4(w[12], w[13], w[14], w[15]), h1, l1);
        ushort* WwH = Wfrag + 2 * 4096;
        ushort* WwL = Wfrag + 3 * 4096;
        *(short8*)(WwH + f * 64 + q * 16) = h0;
        *(short8*)(WwH + f * 64 + q * 16 + 8) = h1;
        *(short8*)(WwL + f * 64 + q * 16) = l0;
        *(short8*)(WwL + f * 64 + q * 16 + 8) = l1;
    }
    // Wt planes (rows of WnT) from LDS: WnT[f][q*16+i] = Wn[q*16+i][f]
    {
        float t[16];
#pragma unroll
        for (int i = 0; i < 16; ++i) t[i] = Wl[(q * 16 + i) * 65 + f];
        short8 h0, l0, h1, l1;
        split8v(make_float4(t[0], t[1], t[2], t[3]),
                make_float4(t[4], t[5], t[6], t[7]), h0, l0);
        split8v(make_float4(t[8], t[9], t[10], t[11]),
                make_float4(t[12], t[13], t[14], t[15]), h1, l1);
        ushort* WtH = Wfrag;
        ushort* WtL = Wfrag + 4096;
        *(short8*)(WtH + f * 64 + q * 16) = h0;
        *(short8*)(WtH + f * 64 + q * 16 + 8) = h1;
        *(short8*)(WtL + f * 64 + q * 16) = l0;
        *(short8*)(WtL + f * 64 + q * 16 + 8) = l1;
    }
}

// ---------------------------------------------------------------------------
// K1: MFMA embed, 384 blocks = (32 tok-grp of 64) x (12 heads); head-fastest
// for L2 x-reuse. Tile 64 tok x 64 out, 4 waves of 16 tok x 64 out each.
// DOUBLE-BUFFERED LDS: one barrier per K-panel; global prefetch issued two
// panels ahead so load latency hides under a full panel of compute+staging.
// ---------------------------------------------------------------------------
__global__ __launch_bounds__(256) void k_embed(const ushort* __restrict__ xsH,
                                               const ushort* __restrict__ xsL,
                                               const ushort* __restrict__ ewH,
                                               const ushort* __restrict__ ewL,
                                               const float* __restrict__ eb,
                                               float* __restrict__ inp) {
    __shared__ ushort AsH[2][64 * 72], AsL[2][64 * 72];
    __shared__ ushort BsH[2][64 * 72], BsL[2][64 * 72];
    const int tid = threadIdx.x;
    const int bid = blockIdx.x;

    const int head = bid % 12;           // fastest -> consecutive blocks share x-tile
    const int tok0 = (bid / 12) * 64;

    const int wv = tid >> 6, lane = tid & 63;
    const int mbase = wv * 16;           // wave's 16-token rows
    const int lm = lane & 15, lq = lane >> 4;

    floatx4 accA[4], accB[4];
#pragma unroll
    for (int nt = 0; nt < 4; ++nt) { accA[nt] = (floatx4)0.f; accB[nt] = (floatx4)0.f; }

    // staging assignment: thread -> row tid>>2 (0..63), k-quarter (tid&3)*16
    const int srow = tid >> 2, skq = (tid & 3) * 16;
    const int off = srow * 72 + skq;
    const ushort* xh = xsH + (size_t)(tok0 + srow) * FIN + skq;
    const ushort* xl = xsL + (size_t)(tok0 + srow) * FIN + skq;
    const ushort* wh = ewH + (size_t)(head * 64 + srow) * FIN + skq;
    const ushort* wl = ewL + (size_t)(head * 64 + srow) * FIN + skq;

    short8 pa[4], pb[4];
    // load + stage panel 0 -> buf 0
    pa[0] = *(const short8*)(xh);  pa[1] = *(const short8*)(xh + 8);
    pa[2] = *(const short8*)(xl);  pa[3] = *(const short8*)(xl + 8);
    pb[0] = *(const short8*)(wh);  pb[1] = *(const short8*)(wh + 8);
    pb[2] = *(const short8*)(wl);  pb[3] = *(const short8*)(wl + 8);
    *(short8*)&AsH[0][off]     = pa[0];
    *(short8*)&AsH[0][off + 8] = pa[1];
    *(short8*)&AsL[0][off]     = pa[2];
    *(short8*)&AsL[0][off + 8] = pa[3];
    *(short8*)&BsH[0][off]     = pb[0];
    *(short8*)&BsH[0][off + 8] = pb[1];
    *(short8*)&BsL[0][off]     = pb[2];
    *(short8*)&BsL[0][off + 8] = pb[3];
    // load panel 1 into regs
    pa[0] = *(const short8*)(xh + 64);  pa[1] = *(const short8*)(xh + 72);
    pa[2] = *(const short8*)(xl + 64);  pa[3] = *(const short8*)(xl + 72);
    pb[0] = *(const short8*)(wh + 64);  pb[1] = *(const short8*)(wh + 72);
    pb[2] = *(const short8*)(wl + 64);  pb[3] = *(const short8*)(wl + 72);
    __syncthreads();

#pragma unroll 2
    for (int kb = 0; kb < 12; ++kb) {
        const int cur = kb & 1;
        // compute panel kb from buf[cur]
#pragma unroll
        for (int ch = 0; ch < 2; ++ch) {
            const int ko = ch * 32 + lq * 8;
            short8 ah = *(const short8*)&AsH[cur][(mbase + lm) * 72 + ko];
            short8 al = *(const short8*)&AsL[cur][(mbase + lm) * 72 + ko];
#pragma unroll
            for (int nt = 0; nt < 4; ++nt) {
                short8 bh = *(const short8*)&BsH[cur][(nt * 16 + lm) * 72 + ko];
                short8 bl = *(const short8*)&BsL[cur][(nt * 16 + lm) * 72 + ko];
                accA[nt] = __builtin_amdgcn_mfma_f32_16x16x32_bf16(ah, bh, accA[nt], 0, 0, 0);
                accB[nt] = __builtin_amdgcn_mfma_f32_16x16x32_bf16(al, bh, accB[nt], 0, 0, 0);
                accB[nt] = __builtin_amdgcn_mfma_f32_16x16x32_bf16(ah, bl, accB[nt], 0, 0, 0);
            }
        }
        if (kb + 1 < 12) {   // stage panel kb+1 -> buf[cur^1] (disjoint from reads)
            *(short8*)&AsH[cur ^ 1][off]     = pa[0];
            *(short8*)&AsH[cur ^ 1][off + 8] = pa[1];
            *(short8*)&AsL[cur ^ 1][off]     = pa[2];
            *(short8*)&AsL[cur ^ 1][off + 8] = pa[3];
            *(short8*)&BsH[cur ^ 1][off]     = pb[0];
            *(short8*)&BsH[cur ^ 1][off + 8] = pb[1];
            *(short8*)&BsL[cur ^ 1][off]     = pb[2];
            *(short8*)&BsL[cur ^ 1][off + 8] = pb[3];
        }
        if (kb + 2 < 12) {   // prefetch panel kb+2 (lands during next panel)
            const int ko = (kb + 2) * 64;
            pa[0] = *(const short8*)(xh + ko);  pa[1] = *(const short8*)(xh + ko + 8);
            pa[2] = *(const short8*)(xl + ko);  pa[3] = *(const short8*)(xl + ko + 8);
            pb[0] = *(const short8*)(wh + ko);  pb[1] = *(const short8*)(wh + ko + 8);
            pb[2] = *(const short8*)(wl + ko);  pb[3] = *(const short8*)(wl + ko + 8);
        }
        __syncthreads();     // single barrier per panel
    }

    // epilogue: bias, clamp, per-token l1norm over 64 outs (wave-internal), store
    float bb[4];
#pragma unroll
    for (int nt = 0; nt < 4; ++nt) bb[nt] = eb[head * 64 + nt * 16 + lm];
    const size_t obase = ((size_t)((tok0 >> 10) * 12 + head) * 1024 + (tok0 & 1023));
#pragma unroll
    for (int r = 0; r < 4; ++r) {
        float e[4];
        float p = 0.f;
#pragma unroll
        for (int nt = 0; nt < 4; ++nt) {
            e[nt] = fmaxf((accA[nt][r] + accB[nt][r]) + bb[nt], 1e-6f);
            p += e[nt];
        }
        p += __shfl_xor(p, 1, 64);
        p += __shfl_xor(p, 2, 64);
        p += __shfl_xor(p, 4, 64);
        p += __shfl_xor(p, 8, 64);
        const float inv = 1.f / fmaxf(p, 1e-20f);
        const int m = mbase + lq * 4 + r;
        float* op = inp + (obase + m) * 64;
#pragma unroll
        for (int nt = 0; nt < 4; ++nt)
            op[nt * 16 + lm] = e[nt] * inv;
    }
}

// ---------------------------------------------------------------------------
// helper: 64x64 matvec via MFMA with split-bf16 B planes in LDS (wave-private T)
// dual accumulator chains for ILP.
// ---------------------------------------------------------------------------
__device__ __forceinline__ void mfma_matvec(const float srcC[4][4], float* T,
                                            int lm, int lq,
                                            const ushort* WH, const ushort* WL,
                                            floatx4 out[4]) {
    __builtin_amdgcn_wave_barrier();
#pragma unroll
    for (int nt = 0; nt < 4; ++nt)
#pragma unroll
        for (int r = 0; r < 4; ++r)
            T[(lq * 4 + r) * 68 + nt * 16 + lm] = srcC[nt][r];
    __builtin_amdgcn_wave_barrier();
    float4 a00 = *(const float4*)&T[lm * 68 + lq * 8];
    float4 a01 = *(const float4*)&T[lm * 68 + lq * 8 + 4];
    float4 a10 = *(const float4*)&T[lm * 68 + 32 + lq * 8];
    float4 a11 = *(const float4*)&T[lm * 68 + 32 + lq * 8 + 4];
    __builtin_amdgcn_wave_barrier();
    short8 A0h, A0l, A1h, A1l;
    split8v(a00, a01, A0h, A0l);
    split8v(a10, a11, A1h, A1l);
#pragma unroll
    for (int nt = 0; nt < 4; ++nt) {
        const int row = (nt * 16 + lm) * 72;
        short8 b0h = *(const short8*)&WH[row + lq * 8];
        short8 b0l = *(const short8*)&WL[row + lq * 8];
        short8 b1h = *(const short8*)&WH[row + 32 + lq * 8];
        short8 b1l = *(const short8*)&WL[row + 32 + lq * 8];
        floatx4 acc0 = (floatx4)0.f, acc1 = (floatx4)0.f;
        acc0 = __builtin_amdgcn_mfma_f32_16x16x32_bf16(A0h, b0h, acc0, 0, 0, 0);
        acc0 = __builtin_amdgcn_mfma_f32_16x16x32_bf16(A0l, b0h, acc0, 0, 0, 0);
        acc0 = __builtin_amdgcn_mfma_f32_16x16x32_bf16(A0h, b0l, acc0, 0, 0, 0);
        acc1 = __builtin_amdgcn_mfma_f32_16x16x32_bf16(A1h, b1h, acc1, 0, 0, 0);
        acc1 = __builtin_amdgcn_mfma_f32_16x16x32_bf16(A1l, b1h, acc1, 0, 0, 0);
        acc1 = __builtin_amdgcn_mfma_f32_16x16x32_bf16(A1h, b1l, acc1, 0, 0, 0);
        out[nt] = acc0 + acc1;
    }
}

// ---------------------------------------------------------------------------
// K3: NNMF updates, 16 tokens per wave, 384 blocks x 4 waves.
// W fragment planes are pre-built (k_conv) — staging is a pure copy.
// ---------------------------------------------------------------------------
__global__ __launch_bounds__(256) void k_nnmf(const float* __restrict__ inp,
                                              const ushort* __restrict__ Wfrag,
                                              const float* __restrict__ r1inv,
                                              float* __restrict__ hout,
                                              float* __restrict__ hriout,
                                              float* __restrict__ mp0) {
    __shared__ ushort WtH[64 * 72], WtL[64 * 72];
    __shared__ ushort WwH[64 * 72], WwL[64 * 72];
    __shared__ float Tb[4][16 * 68];
    __shared__ float pbuf[256];
    const int tid = threadIdx.x, wv = tid >> 6, lane = tid & 63;
    const int lm = lane & 15, lq = lane >> 4;
    float* T = Tb[wv];
    const int rowbase = blockIdx.x * 64 + wv * 16;

    {   // stage W planes: pure copy, thread -> row tid>>2, k-quarter (tid&3)*16
        const int row = tid >> 2, kq = (tid & 3) * 16;
        const int g = row * 64 + kq, l = row * 72 + kq;
        *(short8*)&WtH[l]     = *(const short8*)(Wfrag + g);
        *(short8*)&WtH[l + 8] = *(const short8*)(Wfrag + g + 8);
        *(short8*)&WtL[l]     = *(const short8*)(Wfrag + 4096 + g);
        *(short8*)&WtL[l + 8] = *(const short8*)(Wfrag + 4096 + g + 8);
        *(short8*)&WwH[l]     = *(const short8*)(Wfrag + 8192 + g);
        *(short8*)&WwH[l + 8] = *(const short8*)(Wfrag + 8192 + g + 8);
        *(short8*)&WwL[l]     = *(const short8*)(Wfrag + 12288 + g);
        *(short8*)&WwL[l + 8] = *(const short8*)(Wfrag + 12288 + g + 8);
    }

    float inpC[4][4];
#pragma unroll
    for (int nt = 0; nt < 4; ++nt)
#pragma unroll
        for (int r = 0; r < 4; ++r)
            inpC[nt][r] = inp[(size_t)(rowbase + lq * 4 + r) * 64 + nt * 16 + lm];
    float r1c[4];
#pragma unroll
    for (int nt = 0; nt < 4; ++nt) r1c[nt] = r1inv[nt * 16 + lm];
    __syncthreads();   // W planes ready

    float hC[4][4], recC[4][4];
    {   // ---- iteration 1 (rec1 token-independent) ----
        float qC[4][4];
#pragma unroll
        for (int nt = 0; nt < 4; ++nt)
#pragma unroll
            for (int r = 0; r < 4; ++r) qC[nt][r] = inpC[nt][r] * r1c[nt];
        floatx4 u[4];
        mfma_matvec(qC, T, lm, lq, WwH, WwL, u);
#pragma unroll
        for (int nt = 0; nt < 4; ++nt)
#pragma unroll
            for (int r = 0; r < 4; ++r)
                hC[nt][r] = fmaxf(u[nt][r] * (1.f / 64.f), 1e-6f);
#pragma unroll
        for (int r = 0; r < 4; ++r) {
            float s = (hC[0][r] + hC[1][r]) + (hC[2][r] + hC[3][r]);
            s += __shfl_xor(s, 1, 64); s += __shfl_xor(s, 2, 64);
            s += __shfl_xor(s, 4, 64); s += __shfl_xor(s, 8, 64);
            const float inv = __builtin_amdgcn_rcpf(fmaxf(s, 1e-20f));
#pragma unroll
            for (int nt = 0; nt < 4; ++nt) hC[nt][r] *= inv;
        }
    }
#pragma unroll 1
    for (int it = 0; it < 2; ++it) {   // ---- iterations 2,3 (full) ----
        floatx4 t[4];
        mfma_matvec(hC, T, lm, lq, WtH, WtL, t);
        float tC[4][4], qC[4][4];
#pragma unroll
        for (int nt = 0; nt < 4; ++nt)
#pragma unroll
            for (int r = 0; r < 4; ++r) tC[nt][r] = fmaxf(t[nt][r], 1e-6f);
#pragma unroll
        for (int r = 0; r < 4; ++r) {
            float s = (tC[0][r] + tC[1][r]) + (tC[2][r] + tC[3][r]);
            s += __shfl_xor(s, 1, 64); s += __shfl_xor(s, 2, 64);
            s += __shfl_xor(s, 4, 64); s += __shfl_xor(s, 8, 64);
            s = fmaxf(s, 1e-20f);
            const float invS = __builtin_amdgcn_rcpf(s);
#pragma unroll
            for (int nt = 0; nt < 4; ++nt) {
                recC[nt][r] = tC[nt][r] * invS;
                qC[nt][r] = inpC[nt][r] * s * __builtin_amdgcn_rcpf(tC[nt][r]);
            }
        }
        floatx4 u[4];
        mfma_matvec(qC, T, lm, lq, WwH, WwL, u);
#pragma unroll
        for (int nt = 0; nt < 4; ++nt)
#pragma unroll
            for (int r = 0; r < 4; ++r)
                hC[nt][r] = fmaxf(hC[nt][r] * u[nt][r], 1e-6f);
#pragma unroll
        for (int r = 0; r < 4; ++r) {
            float s = (hC[0][r] + hC[1][r]) + (hC[2][r] + hC[3][r]);
            s += __shfl_xor(s, 1, 64); s += __shfl_xor(s, 2, 64);
            s += __shfl_xor(s, 4, 64); s += __shfl_xor(s, 8, 64);
            const float inv = __builtin_amdgcn_rcpf(fmaxf(s, 1e-20f));
#pragma unroll
            for (int nt = 0; nt < 4; ++nt) hC[nt][r] *= inv;
        }
    }
#pragma unroll
    for (int r = 0; r < 4; ++r) {   // normalize_h
        float s = (hC[0][r] + hC[1][r]) + (hC[2][r] + hC[3][r]);
        s += __shfl_xor(s, 1, 64); s += __shfl_xor(s, 2, 64);
        s += __shfl_xor(s, 4, 64); s += __shfl_xor(s, 8, 64);
        const float inv = __builtin_amdgcn_rcpf(fmaxf(s, 1e-20f));
#pragma unroll
        for (int nt = 0; nt < 4; ++nt) hC[nt][r] *= inv;
    }

    // stores: h, rec*inp row-major [o][f]
#pragma unroll
    for (int nt = 0; nt < 4; ++nt)
#pragma unroll
        for (int r = 0; r < 4; ++r) {
            const size_t o = (size_t)(rowbase + lq * 4 + r) * 64 + nt * 16 + lm;
            hout[o] = hC[nt][r];
            hriout[o] = recC[nt][r] * inpC[nt][r];
        }

    // per-block partial of sum_o h[o,f]: wave-reduce + LDS combine + plain store
    float hs[4];
#pragma unroll
    for (int nt = 0; nt < 4; ++nt) {
        float s = (hC[nt][0] + hC[nt][1]) + (hC[nt][2] + hC[nt][3]);
        s += __shfl_xor(s, 16, 64);
        s += __shfl_xor(s, 32, 64);
        hs[nt] = s;
    }
    pbuf[wv * 64 + lq * 16 + lm] = hs[lq];
    __syncthreads();
    if (tid < 64) {
        float tot = (pbuf[tid] + pbuf[64 + tid]) + (pbuf[128 + tid] + pbuf[192 + tid]);
        mp0[(size_t)blockIdx.x * 64 + tid] = tot;
    }
}

// ---------------------------------------------------------------------------
// K4: one alpha iteration per launch, 384 blocks = (bh) x (64-o chunk).
// All outputs are exclusive plain stores.
// ---------------------------------------------------------------------------
__global__ __launch_bounds__(256) void k_alpha_step(const float* __restrict__ hin,
                                                    const float* __restrict__ hri,
                                                    const float* __restrict__ Wn,
                                                    const float* __restrict__ mp_in,
                                                    float* __restrict__ mp_out,
                                                    float* __restrict__ c,
                                                    int it) {
    __shared__ float mred[4][64];
    __shared__ float mv[64];
    __shared__ float vv[64];
    __shared__ float cl[64];
    const int tid = threadIdx.x;
    const int bh = blockIdx.x >> 4;
    const int chunk = blockIdx.x & 15;
    const size_t rowbase = (size_t)bh * 1024 + chunk * 64;

    {
        int f = tid & 63, p = tid >> 6;
        float s = 0.f;
#pragma unroll
        for (int pp = 0; pp < 4; ++pp)
            s += mp_in[((size_t)bh * 16 + p * 4 + pp) * 64 + f];
        mred[p][f] = s;
    }
    __syncthreads();
    if (tid < 64)
        mv[tid] = (mred[0][tid] + mred[1][tid]) + (mred[2][tid] + mred[3][tid]);
    __syncthreads();
    {
        int d = tid & 63, qq = tid >> 6;
        float r = 0.f;
#pragma unroll
        for (int ff = 0; ff < 16; ++ff)
            r = fmaf(mv[qq * 16 + ff], Wn[(size_t)(qq * 16 + ff) * 64 + d], r);
        mred[qq][d] = r;
    }
    __syncthreads();
    if (tid < 64)
        vv[tid] = 1.f / (((mred[0][tid] + mred[1][tid]) + (mred[2][tid] + mred[3][tid])) + 1e-20f);
    __syncthreads();
    {
        int o = tid >> 2, dq = tid & 3;
        const float* rp = hri + (rowbase + o) * 64 + dq * 16;
        float dot = 0.f;
#pragma unroll
        for (int t4 = 0; t4 < 16; t4 += 4) {
            float4 r4 = *(const float4*)(rp + t4);
            dot = fmaf(r4.x, vv[dq * 16 + t4 + 0], dot);
            dot = fmaf(r4.y, vv[dq * 16 + t4 + 1], dot);
            dot = fmaf(r4.z, vv[dq * 16 + t4 + 2], dot);
            dot = fmaf(r4.w, vv[dq * 16 + t4 + 3], dot);
        }
        dot += __shfl_xor(dot, 1, 64);
        dot += __shfl_xor(dot, 2, 64);
        float cn = dot;
        if (it >= 2) cn *= c[rowbase + o];
        if (dq == 0) { c[rowbase + o] = cn; cl[o] = cn; }
    }
    __syncthreads();
    {
        const int f4 = (tid & 15) * 4, ogr = tid >> 4;
        float4 a = make_float4(0.f, 0.f, 0.f, 0.f);
#pragma unroll
        for (int oi = 0; oi < 4; ++oi) {
            int o = ogr * 4 + oi;
            float4 h4 = *(const float4*)(hin + (rowbase + o) * 64 + f4);
            float cv = cl[o];
            a.x = fmaf(h4.x, cv, a.x); a.y = fmaf(h4.y, cv, a.y);
            a.z = fmaf(h4.z, cv, a.z); a.w = fmaf(h4.w, cv, a.w);
        }
        a.x += __shfl_xor(a.x, 16, 64); a.y += __shfl_xor(a.y, 16, 64);
        a.z += __shfl_xor(a.z, 16, 64); a.w += __shfl_xor(a.w, 16, 64);
        a.x += __shfl_xor(a.x, 32, 64); a.y += __shfl_xor(a.y, 32, 64);
        a.z += __shfl_xor(a.z, 32, 64); a.w += __shfl_xor(a.w, 32, 64);
        const int w = tid >> 6;
        if ((tid & 63) < 16) *(float4*)&mred[w][(tid & 15) * 4] = a;
    }
    __syncthreads();
    if (tid < 64) {
        float s = (mred[0][tid] + mred[1][tid]) + (mred[2][tid] + mred[3][tid]);
        mp_out[((size_t)bh * 16 + chunk) * 64 + tid] = s;
    }
}

// ---------------------------------------------------------------------------
// K5: out-projection + broadcast, 384 blocks = (b) x (12 out-seg) x (16 rowgrp).
// Folds the final 16-chunk M reduction into the Ml load.
// ---------------------------------------------------------------------------
__global__ __launch_bounds__(256) void k_projbcast(const float* __restrict__ mp3,
                                                   const float* __restrict__ ow,
                                                   const float* __restrict__ ob,
                                                   float* __restrict__ out) {
    __shared__ float Ml[768];
    __shared__ float ps[4][64];
    __shared__ float yseg[64];
    const int tid = threadIdx.x;
    const int b = blockIdx.x / 192;
    const int rem = blockIdx.x - b * 192;
    const int jt = rem >> 4, rg = rem & 15;
    for (int i = tid; i < 768; i += 256) {
        const int hh = i >> 6, f = i & 63;
        const float* src = mp3 + ((size_t)(b * 12 + hh) * 16) * 64 + f;
        float s = 0.f;
#pragma unroll
        for (int cc = 0; cc < 16; ++cc) s += src[cc * 64];
        Ml[i] = s;
    }
    __syncthreads();
    const int jj = tid & 63, part = tid >> 6;
    const int j = jt * 64 + jj;
    const float* row = ow + (size_t)j * 768 + part * 192;
    float acc = 0.f;
    for (int t = 0; t < 192; t += 4) {
        float4 w4 = *(const float4*)(row + t);
        acc = fmaf(w4.x, Ml[part * 192 + t + 0], acc);
        acc = fmaf(w4.y, Ml[part * 192 + t + 1], acc);
        acc = fmaf(w4.z, Ml[part * 192 + t + 2], acc);
        acc = fmaf(w4.w, Ml[part * 192 + t + 3], acc);
    }
    ps[part][jj] = acc;
    __syncthreads();
    if (tid < 64)
        yseg[tid] = ps[0][tid] + ps[1][tid] + ps[2][tid] + ps[3][tid] + ob[jt * 64 + tid];
    __syncthreads();
    const int r0 = tid >> 2, c4 = (tid & 3) * 16;
    float4 v4[4];
#pragma unroll
    for (int q = 0; q < 4; ++q) v4[q] = *(const float4*)&yseg[c4 + q * 4];
    float* dst = out + ((size_t)(b * 1024 + rg * 64 + r0)) * 768 + jt * 64 + c4;
#pragma unroll
    for (int q = 0; q < 4; ++q) *(float4*)(dst + q * 4) = v4[q];
}

extern "C" void kernel_launch(void* const* d_in, const int* in_sizes, int n_in,
                              void* d_out, int out_size, void* d_ws, size_t ws_size,
                              hipStream_t stream) {
    const float* xs = (const float*)d_in[0];  // [2,1024,768]
    const float* ew = (const float*)d_in[1];  // [768,768]
    const float* eb = (const float*)d_in[2];  // [768]
    const float* nw = (const float*)d_in[3];  // [64,64]
    const float* ow = (const float*)d_in[4];  // [768,768]
    const float* ob = (const float*)d_in[5];  // [768]
    float* out = (float*)d_out;               // [2,1024,768]

    float* ws    = (float*)d_ws;
    float* inp   = ws;                     // 1572864 f
    float* h     = ws + 1572864;           // 1572864 f
    float* hri   = ws + 3145728;           // 1572864 f
    float* Wn    = ws + 4718592;           // 4096 f
    float* r1inv = ws + 4722688;           // 256 f
    float* mp0   = ws + 4722944;           // 24576 f
    float* mp1   = ws + 4747520;           // 24576 f
    float* mp2   = ws + 4772096;           // 24576 f
    float* c     = ws + 4796672;           // 24576 f
    ushort* xsH  = (ushort*)(ws + 4821248);    // 1572864 us (786432 f)
    ushort* xsL  = (ushort*)(ws + 5607680);    // 1572864 us
    ushort* ewH  = (ushort*)(ws + 6394112);    // 589824 us (294912 f)
    ushort* ewL  = (ushort*)(ws + 6689024);    // 589824 us
    ushort* Wfrag= (ushort*)(ws + 6983936);    // 16384 us (8192 f)

    k_conv<<<1057, 256, 0, stream>>>(xs, ew, nw, xsH, xsL, ewH, ewL, Wn, r1inv, Wfrag);
    k_embed<<<384, 256, 0, stream>>>(xsH, xsL, ewH, ewL, eb, inp);
    k_nnmf<<<384, 256, 0, stream>>>(inp, Wfrag, r1inv, h, hri, mp0);
    k_alpha_step<<<384, 256, 0, stream>>>(h, hri, Wn, mp0, mp1, c, 1);
    k_alpha_step<<<384, 256, 0, stream>>>(h, hri, Wn, mp1, mp2, c, 2);
    k_alpha_step<<<384, 256, 0, stream>>>(h, hri, Wn, mp2, mp1, c, 3);
    k_projbcast<<<384, 256, 0, stream>>>(mp1, ow, ob, out);
}

// Round 10
// 127.782 us; speedup vs baseline: 1.2895x; 1.0291x over previous
//
#include <hip/hip_runtime.h>

// Problem constants
#define B_  2
#define S_  1024
#define FIN 768
#define E_  768
#define H_  12
#define DH  64   // = FH = 64

typedef unsigned int uint;
typedef unsigned short ushort;
typedef __attribute__((ext_vector_type(8))) short short8;    // 8 bf16 (4 VGPRs)
typedef __attribute__((ext_vector_type(4))) float floatx4;   // MFMA acc

__device__ __forceinline__ ushort f2bf(float f) {   // RNE float->bf16 bits
    uint u = __float_as_uint(f);
    return (ushort)((u + 0x7fffu + ((u >> 16) & 1u)) >> 16);
}

__device__ __forceinline__ uint4 pack8(const ushort* p) {
    uint4 r;
    r.x = (uint)p[0] | ((uint)p[1] << 16);
    r.y = (uint)p[2] | ((uint)p[3] << 16);
    r.z = (uint)p[4] | ((uint)p[5] << 16);
    r.w = (uint)p[6] | ((uint)p[7] << 16);
    return r;
}

__device__ __forceinline__ void split8v(float4 a, float4 b, short8& hi, short8& lo) {
    float v[8] = {a.x, a.y, a.z, a.w, b.x, b.y, b.z, b.w};
    ushort h[8], l[8];
#pragma unroll
    for (int j = 0; j < 8; ++j) {
        h[j] = f2bf(v[j]);
        l[j] = f2bf(v[j] - __uint_as_float(((uint)h[j]) << 16));
    }
    uint4 H = pack8(h), L = pack8(l);
    hi = *(short8*)&H;
    lo = *(short8*)&L;
}

// ---------------------------------------------------------------------------
// K0: conversion + prep pass. blocks 0..767: xs -> xsH/xsL bf16 split planes.
// blocks 768..1055: ew -> ewH/ewL. block 1056: W-prep (Wn, r1inv, Wfrag).
// ---------------------------------------------------------------------------
__global__ __launch_bounds__(256) void k_conv(const float* __restrict__ xs,
                                              const float* __restrict__ ew,
                                              const float* __restrict__ nw,
                                              ushort* __restrict__ xsH,
                                              ushort* __restrict__ xsL,
                                              ushort* __restrict__ ewH,
                                              ushort* __restrict__ ewL,
                                              float* __restrict__ Wn,
                                              float* __restrict__ r1inv,
                                              ushort* __restrict__ Wfrag) {
    __shared__ float Wl[64 * 65];
    const int tid = threadIdx.x, bid = blockIdx.x;

    if (bid < 768) {          // xs conversion: 2048x768 / 8 per thread
        const size_t i = ((size_t)bid * 256 + tid) * 8;
        short8 hi, lo;
        split8v(*(const float4*)(xs + i), *(const float4*)(xs + i + 4), hi, lo);
        *(short8*)(xsH + i) = hi;
        *(short8*)(xsL + i) = lo;
        return;
    }
    if (bid < 1056) {         // ew conversion: 768x768 / 8 per thread
        const size_t i = ((size_t)(bid - 768) * 256 + tid) * 8;
        short8 hi, lo;
        split8v(*(const float4*)(ew + i), *(const float4*)(ew + i + 4), hi, lo);
        *(short8*)(ewH + i) = hi;
        *(short8*)(ewL + i) = lo;
        return;
    }

    // ---- prep block (bid == 1056) ----
    const int f = tid >> 2, q = tid & 3;
    float v[16];
    float s = 0.f;
#pragma unroll
    for (int i = 0; i < 16; ++i) { v[i] = nw[f * 64 + q * 16 + i]; s += v[i]; }
    s += __shfl_xor(s, 1, 64);
    s += __shfl_xor(s, 2, 64);
    const float inv = 1.f / fmaxf(s, 1e-20f);
    float w[16];
#pragma unroll
    for (int i = 0; i < 16; ++i) {
        w[i] = v[i] * inv;
        Wn[f * 64 + q * 16 + i] = w[i];
        Wl[f * 65 + q * 16 + i] = w[i];
    }
    __syncthreads();
    if (tid < 64) {
        float cs = 0.f;
        for (int ff = 0; ff < 64; ++ff) cs += Wl[ff * 65 + tid];
        float t = fmaxf(cs * (1.f / 64.f), 1e-6f);
        float S = t;
#pragma unroll
        for (int m = 1; m < 64; m <<= 1) S += __shfl_xor(S, m, 64);
        S = fmaxf(S, 1e-20f);
        r1inv[tid] = S / t;   // 1/rec1
    }
    // Ww planes (rows of Wn) from registers: row f, quarter q
    {
        short8 h0, l0, h1, l1;
        split8v(make_float4(w[0], w[1], w[2], w[3]),
                make_float4(w[4], w[5], w[6], w[7]), h0, l0);
        split8v(make_float4(w[8], w[9], w[10], w[11]),
                make_float4(w[12], w[13], w[14], w[15]), h1, l1);
        ushort* WwH = Wfrag + 2 * 4096;
        ushort* WwL = Wfrag + 3 * 4096;
        *(short8*)(WwH + f * 64 + q * 16) = h0;
        *(short8*)(WwH + f * 64 + q * 16 + 8) = h1;
        *(short8*)(WwL + f * 64 + q * 16) = l0;
        *(short8*)(WwL + f * 64 + q * 16 + 8) = l1;
    }
    // Wt planes (rows of WnT) from LDS: WnT[f][q*16+i] = Wn[q*16+i][f]
    {
        float t[16];
#pragma unroll
        for (int i = 0; i < 16; ++i) t[i] = Wl[(q * 16 + i) * 65 + f];
        short8 h0, l0, h1, l1;
        split8v(make_float4(t[0], t[1], t[2], t[3]),
                make_float4(t[4], t[5], t[6], t[7]), h0, l0);
        split8v(make_float4(t[8], t[9], t[10], t[11]),
                make_float4(t[12], t[13], t[14], t[15]), h1, l1);
        ushort* WtH = Wfrag;
        ushort* WtL = Wfrag + 4096;
        *(short8*)(WtH + f * 64 + q * 16) = h0;
        *(short8*)(WtH + f * 64 + q * 16 + 8) = h1;
        *(short8*)(WtL + f * 64 + q * 16) = l0;
        *(short8*)(WtL + f * 64 + q * 16 + 8) = l1;
    }
}

// ---------------------------------------------------------------------------
// helper: 64x64 matvec via MFMA with split-bf16 B planes in LDS (wave-private T)
// dual accumulator chains for ILP.
// ---------------------------------------------------------------------------
__device__ __forceinline__ void mfma_matvec(const float srcC[4][4], float* T,
                                            int lm, int lq,
                                            const ushort* WH, const ushort* WL,
                                            floatx4 out[4]) {
    __builtin_amdgcn_wave_barrier();
#pragma unroll
    for (int nt = 0; nt < 4; ++nt)
#pragma unroll
        for (int r = 0; r < 4; ++r)
            T[(lq * 4 + r) * 68 + nt * 16 + lm] = srcC[nt][r];
    __builtin_amdgcn_wave_barrier();
    float4 a00 = *(const float4*)&T[lm * 68 + lq * 8];
    float4 a01 = *(const float4*)&T[lm * 68 + lq * 8 + 4];
    float4 a10 = *(const float4*)&T[lm * 68 + 32 + lq * 8];
    float4 a11 = *(const float4*)&T[lm * 68 + 32 + lq * 8 + 4];
    __builtin_amdgcn_wave_barrier();
    short8 A0h, A0l, A1h, A1l;
    split8v(a00, a01, A0h, A0l);
    split8v(a10, a11, A1h, A1l);
#pragma unroll
    for (int nt = 0; nt < 4; ++nt) {
        const int row = (nt * 16 + lm) * 72;
        short8 b0h = *(const short8*)&WH[row + lq * 8];
        short8 b0l = *(const short8*)&WL[row + lq * 8];
        short8 b1h = *(const short8*)&WH[row + 32 + lq * 8];
        short8 b1l = *(const short8*)&WL[row + 32 + lq * 8];
        floatx4 acc0 = (floatx4)0.f, acc1 = (floatx4)0.f;
        acc0 = __builtin_amdgcn_mfma_f32_16x16x32_bf16(A0h, b0h, acc0, 0, 0, 0);
        acc0 = __builtin_amdgcn_mfma_f32_16x16x32_bf16(A0l, b0h, acc0, 0, 0, 0);
        acc0 = __builtin_amdgcn_mfma_f32_16x16x32_bf16(A0h, b0l, acc0, 0, 0, 0);
        acc1 = __builtin_amdgcn_mfma_f32_16x16x32_bf16(A1h, b1h, acc1, 0, 0, 0);
        acc1 = __builtin_amdgcn_mfma_f32_16x16x32_bf16(A1l, b1h, acc1, 0, 0, 0);
        acc1 = __builtin_amdgcn_mfma_f32_16x16x32_bf16(A1h, b1l, acc1, 0, 0, 0);
        out[nt] = acc0 + acc1;
    }
}

// ---------------------------------------------------------------------------
// K1 fused: embed + NNMF in one kernel. 384 blocks = (32 tok-grp of 64) x
// (12 heads), identical decomposition for both phases — embed's epilogue
// registers ARE nnmf's inpC (no inp global round-trip, one fewer launch).
// LDS time-sliced: embed dbuf (73.7 KB) -> nnmf W-planes + T (55.3 KB).
// ---------------------------------------------------------------------------
__global__ __launch_bounds__(256) void k_embed_nnmf(const ushort* __restrict__ xsH,
                                                    const ushort* __restrict__ xsL,
                                                    const ushort* __restrict__ ewH,
                                                    const ushort* __restrict__ ewL,
                                                    const float* __restrict__ eb,
                                                    const ushort* __restrict__ Wfrag,
                                                    const float* __restrict__ r1inv,
                                                    float* __restrict__ hout,
                                                    float* __restrict__ hriout,
                                                    float* __restrict__ mp0) {
    __shared__ __align__(16) unsigned char smem[73728];
    ushort* const sm = (ushort*)smem;
    const int tid = threadIdx.x;
    const int bid = blockIdx.x;

    const int head = bid % 12;           // fastest -> consecutive blocks share x-tile
    const int tok0 = (bid / 12) * 64;

    const int wv = tid >> 6, lane = tid & 63;
    const int mbase = wv * 16;           // wave's 16-token rows
    const int lm = lane & 15, lq = lane >> 4;

    floatx4 accA[4], accB[4];
#pragma unroll
    for (int nt = 0; nt < 4; ++nt) { accA[nt] = (floatx4)0.f; accB[nt] = (floatx4)0.f; }

    // ---- embed phase (double-buffered LDS, 1 barrier/panel) ----
    // buffer layout: buf stride 18432 ushorts; planes AsH,AsL,BsH,BsL at +0,+4608,+9216,+13824
    const int srow = tid >> 2, skq = (tid & 3) * 16;
    const int off = srow * 72 + skq;
    const ushort* xh = xsH + (size_t)(tok0 + srow) * FIN + skq;
    const ushort* xl = xsL + (size_t)(tok0 + srow) * FIN + skq;
    const ushort* wh = ewH + (size_t)(head * 64 + srow) * FIN + skq;
    const ushort* wl = ewL + (size_t)(head * 64 + srow) * FIN + skq;

    short8 pa[4], pb[4];
    pa[0] = *(const short8*)(xh);  pa[1] = *(const short8*)(xh + 8);
    pa[2] = *(const short8*)(xl);  pa[3] = *(const short8*)(xl + 8);
    pb[0] = *(const short8*)(wh);  pb[1] = *(const short8*)(wh + 8);
    pb[2] = *(const short8*)(wl);  pb[3] = *(const short8*)(wl + 8);
    {
        ushort* b0 = sm;
        *(short8*)&b0[off]            = pa[0];
        *(short8*)&b0[off + 8]        = pa[1];
        *(short8*)&b0[4608 + off]     = pa[2];
        *(short8*)&b0[4608 + off + 8] = pa[3];
        *(short8*)&b0[9216 + off]     = pb[0];
        *(short8*)&b0[9216 + off + 8] = pb[1];
        *(short8*)&b0[13824 + off]    = pb[2];
        *(short8*)&b0[13824 + off + 8]= pb[3];
    }
    pa[0] = *(const short8*)(xh + 64);  pa[1] = *(const short8*)(xh + 72);
    pa[2] = *(const short8*)(xl + 64);  pa[3] = *(const short8*)(xl + 72);
    pb[0] = *(const short8*)(wh + 64);  pb[1] = *(const short8*)(wh + 72);
    pb[2] = *(const short8*)(wl + 64);  pb[3] = *(const short8*)(wl + 72);
    __syncthreads();

#pragma unroll 2
    for (int kb = 0; kb < 12; ++kb) {
        const int cur = kb & 1;
        const ushort* cb = sm + cur * 18432;
#pragma unroll
        for (int ch = 0; ch < 2; ++ch) {
            const int ko = ch * 32 + lq * 8;
            short8 ah = *(const short8*)&cb[(mbase + lm) * 72 + ko];
            short8 al = *(const short8*)&cb[4608 + (mbase + lm) * 72 + ko];
#pragma unroll
            for (int nt = 0; nt < 4; ++nt) {
                short8 bh = *(const short8*)&cb[9216 + (nt * 16 + lm) * 72 + ko];
                short8 bl = *(const short8*)&cb[13824 + (nt * 16 + lm) * 72 + ko];
                accA[nt] = __builtin_amdgcn_mfma_f32_16x16x32_bf16(ah, bh, accA[nt], 0, 0, 0);
                accB[nt] = __builtin_amdgcn_mfma_f32_16x16x32_bf16(al, bh, accB[nt], 0, 0, 0);
                accB[nt] = __builtin_amdgcn_mfma_f32_16x16x32_bf16(ah, bl, accB[nt], 0, 0, 0);
            }
        }
        if (kb + 1 < 12) {
            ushort* sb = sm + (cur ^ 1) * 18432;
            *(short8*)&sb[off]            = pa[0];
            *(short8*)&sb[off + 8]        = pa[1];
            *(short8*)&sb[4608 + off]     = pa[2];
            *(short8*)&sb[4608 + off + 8] = pa[3];
            *(short8*)&sb[9216 + off]     = pb[0];
            *(short8*)&sb[9216 + off + 8] = pb[1];
            *(short8*)&sb[13824 + off]    = pb[2];
            *(short8*)&sb[13824 + off + 8]= pb[3];
        }
        if (kb + 2 < 12) {
            const int ko = (kb + 2) * 64;
            pa[0] = *(const short8*)(xh + ko);  pa[1] = *(const short8*)(xh + ko + 8);
            pa[2] = *(const short8*)(xl + ko);  pa[3] = *(const short8*)(xl + ko + 8);
            pb[0] = *(const short8*)(wh + ko);  pb[1] = *(const short8*)(wh + ko + 8);
            pb[2] = *(const short8*)(wl + ko);  pb[3] = *(const short8*)(wl + ko + 8);
        }
        __syncthreads();
    }

    // prefetch W fragment planes + r1inv during the epilogue (LDS still busy)
    const int wrow = tid >> 2, wkq = (tid & 3) * 16;
    const int wg = wrow * 64 + wkq;
    short8 wt0 = *(const short8*)(Wfrag + wg);
    short8 wt1 = *(const short8*)(Wfrag + wg + 8);
    short8 wt2 = *(const short8*)(Wfrag + 4096 + wg);
    short8 wt3 = *(const short8*)(Wfrag + 4096 + wg + 8);
    short8 ww0 = *(const short8*)(Wfrag + 8192 + wg);
    short8 ww1 = *(const short8*)(Wfrag + 8192 + wg + 8);
    short8 ww2 = *(const short8*)(Wfrag + 12288 + wg);
    short8 ww3 = *(const short8*)(Wfrag + 12288 + wg + 8);
    float r1c[4];
#pragma unroll
    for (int nt = 0; nt < 4; ++nt) r1c[nt] = r1inv[nt * 16 + lm];

    // embed epilogue: bias, clamp, per-token l1norm (wave-internal) -> inpC regs
    float inpC[4][4];
    {
        float bb[4];
#pragma unroll
        for (int nt = 0; nt < 4; ++nt) bb[nt] = eb[head * 64 + nt * 16 + lm];
#pragma unroll
        for (int r = 0; r < 4; ++r) {
            float e[4];
            float p = 0.f;
#pragma unroll
            for (int nt = 0; nt < 4; ++nt) {
                e[nt] = fmaxf((accA[nt][r] + accB[nt][r]) + bb[nt], 1e-6f);
                p += e[nt];
            }
            p += __shfl_xor(p, 1, 64);
            p += __shfl_xor(p, 2, 64);
            p += __shfl_xor(p, 4, 64);
            p += __shfl_xor(p, 8, 64);
            const float inv = 1.f / fmaxf(p, 1e-20f);
#pragma unroll
            for (int nt = 0; nt < 4; ++nt) inpC[nt][r] = e[nt] * inv;
        }
    }

    // ---- re-carve LDS for nnmf phase ----
    __syncthreads();   // embed buffers dead
    ushort* WtH = sm;                         // [64][72] each
    ushort* WtL = sm + 4608;
    ushort* WwH = sm + 9216;
    ushort* WwL = sm + 13824;
    float*  Tb  = (float*)(smem + 36864);     // 4 waves x [16*68]
    float*  pbuf= (float*)(smem + 54272);     // [256]
    float*  T   = Tb + wv * (16 * 68);
    {
        const int l = wrow * 72 + wkq;
        *(short8*)&WtH[l]     = wt0;
        *(short8*)&WtH[l + 8] = wt1;
        *(short8*)&WtL[l]     = wt2;
        *(short8*)&WtL[l + 8] = wt3;
        *(short8*)&WwH[l]     = ww0;
        *(short8*)&WwH[l + 8] = ww1;
        *(short8*)&WwL[l]     = ww2;
        *(short8*)&WwL[l + 8] = ww3;
    }
    __syncthreads();   // W planes ready

    const size_t obase = ((size_t)((tok0 >> 10) * 12 + head) * 1024 + (tok0 & 1023));
    const size_t rowbase = obase + wv * 16;

    float hC[4][4], recC[4][4];
    {   // ---- iteration 1 (rec1 token-independent) ----
        float qC[4][4];
#pragma unroll
        for (int nt = 0; nt < 4; ++nt)
#pragma unroll
            for (int r = 0; r < 4; ++r) qC[nt][r] = inpC[nt][r] * r1c[nt];
        floatx4 u[4];
        mfma_matvec(qC, T, lm, lq, WwH, WwL, u);
#pragma unroll
        for (int nt = 0; nt < 4; ++nt)
#pragma unroll
            for (int r = 0; r < 4; ++r)
                hC[nt][r] = fmaxf(u[nt][r] * (1.f / 64.f), 1e-6f);
#pragma unroll
        for (int r = 0; r < 4; ++r) {
            float s = (hC[0][r] + hC[1][r]) + (hC[2][r] + hC[3][r]);
            s += __shfl_xor(s, 1, 64); s += __shfl_xor(s, 2, 64);
            s += __shfl_xor(s, 4, 64); s += __shfl_xor(s, 8, 64);
            const float inv = __builtin_amdgcn_rcpf(fmaxf(s, 1e-20f));
#pragma unroll
            for (int nt = 0; nt < 4; ++nt) hC[nt][r] *= inv;
        }
    }
#pragma unroll 1
    for (int it = 0; it < 2; ++it) {   // ---- iterations 2,3 (full) ----
        floatx4 t[4];
        mfma_matvec(hC, T, lm, lq, WtH, WtL, t);
        float tC[4][4], qC[4][4];
#pragma unroll
        for (int nt = 0; nt < 4; ++nt)
#pragma unroll
            for (int r = 0; r < 4; ++r) tC[nt][r] = fmaxf(t[nt][r], 1e-6f);
#pragma unroll
        for (int r = 0; r < 4; ++r) {
            float s = (tC[0][r] + tC[1][r]) + (tC[2][r] + tC[3][r]);
            s += __shfl_xor(s, 1, 64); s += __shfl_xor(s, 2, 64);
            s += __shfl_xor(s, 4, 64); s += __shfl_xor(s, 8, 64);
            s = fmaxf(s, 1e-20f);
            const float invS = __builtin_amdgcn_rcpf(s);
#pragma unroll
            for (int nt = 0; nt < 4; ++nt) {
                recC[nt][r] = tC[nt][r] * invS;
                qC[nt][r] = inpC[nt][r] * s * __builtin_amdgcn_rcpf(tC[nt][r]);
            }
        }
        floatx4 u[4];
        mfma_matvec(qC, T, lm, lq, WwH, WwL, u);
#pragma unroll
        for (int nt = 0; nt < 4; ++nt)
#pragma unroll
            for (int r = 0; r < 4; ++r)
                hC[nt][r] = fmaxf(hC[nt][r] * u[nt][r], 1e-6f);
#pragma unroll
        for (int r = 0; r < 4; ++r) {
            float s = (hC[0][r] + hC[1][r]) + (hC[2][r] + hC[3][r]);
            s += __shfl_xor(s, 1, 64); s += __shfl_xor(s, 2, 64);
            s += __shfl_xor(s, 4, 64); s += __shfl_xor(s, 8, 64);
            const float inv = __builtin_amdgcn_rcpf(fmaxf(s, 1e-20f));
#pragma unroll
            for (int nt = 0; nt < 4; ++nt) hC[nt][r] *= inv;
        }
    }
#pragma unroll
    for (int r = 0; r < 4; ++r) {   // normalize_h
        float s = (hC[0][r] + hC[1][r]) + (hC[2][r] + hC[3][r]);
        s += __shfl_xor(s, 1, 64); s += __shfl_xor(s, 2, 64);
        s += __shfl_xor(s, 4, 64); s += __shfl_xor(s, 8, 64);
        const float inv = __builtin_amdgcn_rcpf(fmaxf(s, 1e-20f));
#pragma unroll
        for (int nt = 0; nt < 4; ++nt) hC[nt][r] *= inv;
    }

    // stores: h, rec*inp row-major [o][f]
#pragma unroll
    for (int nt = 0; nt < 4; ++nt)
#pragma unroll
        for (int r = 0; r < 4; ++r) {
            const size_t o = (rowbase + lq * 4 + r) * 64 + nt * 16 + lm;
            hout[o] = hC[nt][r];
            hriout[o] = recC[nt][r] * inpC[nt][r];
        }

    // per-block partial of sum_o h[o,f]: wave-reduce + LDS combine + plain store
    float hs[4];
#pragma unroll
    for (int nt = 0; nt < 4; ++nt) {
        float s = (hC[nt][0] + hC[nt][1]) + (hC[nt][2] + hC[nt][3]);
        s += __shfl_xor(s, 16, 64);
        s += __shfl_xor(s, 32, 64);
        hs[nt] = s;
    }
    pbuf[wv * 64 + lq * 16 + lm] = hs[lq];
    __syncthreads();
    if (tid < 64) {
        float tot = (pbuf[tid] + pbuf[64 + tid]) + (pbuf[128 + tid] + pbuf[192 + tid]);
        mp0[(obase >> 6) * 64 + tid] = tot;
    }
}

// ---------------------------------------------------------------------------
// K4: one alpha iteration per launch, 384 blocks = (bh) x (64-o chunk).
// All outputs are exclusive plain stores.
// ---------------------------------------------------------------------------
__global__ __launch_bounds__(256) void k_alpha_step(const float* __restrict__ hin,
                                                    const float* __restrict__ hri,
                                                    const float* __restrict__ Wn,
                                                    const float* __restrict__ mp_in,
                                                    float* __restrict__ mp_out,
                                                    float* __restrict__ c,
                                                    int it) {
    __shared__ float mred[4][64];
    __shared__ float mv[64];
    __shared__ float vv[64];
    __shared__ float cl[64];
    const int tid = threadIdx.x;
    const int bh = blockIdx.x >> 4;
    const int chunk = blockIdx.x & 15;
    const size_t rowbase = (size_t)bh * 1024 + chunk * 64;

    {
        int f = tid & 63, p = tid >> 6;
        float s = 0.f;
#pragma unroll
        for (int pp = 0; pp < 4; ++pp)
            s += mp_in[((size_t)bh * 16 + p * 4 + pp) * 64 + f];
        mred[p][f] = s;
    }
    __syncthreads();
    if (tid < 64)
        mv[tid] = (mred[0][tid] + mred[1][tid]) + (mred[2][tid] + mred[3][tid]);
    __syncthreads();
    {
        int d = tid & 63, qq = tid >> 6;
        float r = 0.f;
#pragma unroll
        for (int ff = 0; ff < 16; ++ff)
            r = fmaf(mv[qq * 16 + ff], Wn[(size_t)(qq * 16 + ff) * 64 + d], r);
        mred[qq][d] = r;
    }
    __syncthreads();
    if (tid < 64)
        vv[tid] = 1.f / (((mred[0][tid] + mred[1][tid]) + (mred[2][tid] + mred[3][tid])) + 1e-20f);
    __syncthreads();
    {
        int o = tid >> 2, dq = tid & 3;
        const float* rp = hri + (rowbase + o) * 64 + dq * 16;
        float dot = 0.f;
#pragma unroll
        for (int t4 = 0; t4 < 16; t4 += 4) {
            float4 r4 = *(const float4*)(rp + t4);
            dot = fmaf(r4.x, vv[dq * 16 + t4 + 0], dot);
            dot = fmaf(r4.y, vv[dq * 16 + t4 + 1], dot);
            dot = fmaf(r4.z, vv[dq * 16 + t4 + 2], dot);
            dot = fmaf(r4.w, vv[dq * 16 + t4 + 3], dot);
        }
        dot += __shfl_xor(dot, 1, 64);
        dot += __shfl_xor(dot, 2, 64);
        float cn = dot;
        if (it >= 2) cn *= c[rowbase + o];
        if (dq == 0) { c[rowbase + o] = cn; cl[o] = cn; }
    }
    __syncthreads();
    {
        const int f4 = (tid & 15) * 4, ogr = tid >> 4;
        float4 a = make_float4(0.f, 0.f, 0.f, 0.f);
#pragma unroll
        for (int oi = 0; oi < 4; ++oi) {
            int o = ogr * 4 + oi;
            float4 h4 = *(const float4*)(hin + (rowbase + o) * 64 + f4);
            float cv = cl[o];
            a.x = fmaf(h4.x, cv, a.x); a.y = fmaf(h4.y, cv, a.y);
            a.z = fmaf(h4.z, cv, a.z); a.w = fmaf(h4.w, cv, a.w);
        }
        a.x += __shfl_xor(a.x, 16, 64); a.y += __shfl_xor(a.y, 16, 64);
        a.z += __shfl_xor(a.z, 16, 64); a.w += __shfl_xor(a.w, 16, 64);
        a.x += __shfl_xor(a.x, 32, 64); a.y += __shfl_xor(a.y, 32, 64);
        a.z += __shfl_xor(a.z, 32, 64); a.w += __shfl_xor(a.w, 32, 64);
        const int w = tid >> 6;
        if ((tid & 63) < 16) *(float4*)&mred[w][(tid & 15) * 4] = a;
    }
    __syncthreads();
    if (tid < 64) {
        float s = (mred[0][tid] + mred[1][tid]) + (mred[2][tid] + mred[3][tid]);
        mp_out[((size_t)bh * 16 + chunk) * 64 + tid] = s;
    }
}

// ---------------------------------------------------------------------------
// K5: out-projection + broadcast, 384 blocks = (b) x (12 out-seg) x (16 rowgrp).
// Folds the final 16-chunk M reduction into the Ml load.
// ---------------------------------------------------------------------------
__global__ __launch_bounds__(256) void k_projbcast(const float* __restrict__ mp3,
                                                   const float* __restrict__ ow,
                                                   const float* __restrict__ ob,
                                                   float* __restrict__ out) {
    __shared__ float Ml[768];
    __shared__ float ps[4][64];
    __shared__ float yseg[64];
    const int tid = threadIdx.x;
    const int b = blockIdx.x / 192;
    const int rem = blockIdx.x - b * 192;
    const int jt = rem >> 4, rg = rem & 15;
    for (int i = tid; i < 768; i += 256) {
        const int hh = i >> 6, f = i & 63;
        const float* src = mp3 + ((size_t)(b * 12 + hh) * 16) * 64 + f;
        float s = 0.f;
#pragma unroll
        for (int cc = 0; cc < 16; ++cc) s += src[cc * 64];
        Ml[i] = s;
    }
    __syncthreads();
    const int jj = tid & 63, part = tid >> 6;
    const int j = jt * 64 + jj;
    const float* row = ow + (size_t)j * 768 + part * 192;
    float acc = 0.f;
    for (int t = 0; t < 192; t += 4) {
        float4 w4 = *(const float4*)(row + t);
        acc = fmaf(w4.x, Ml[part * 192 + t + 0], acc);
        acc = fmaf(w4.y, Ml[part * 192 + t + 1], acc);
        acc = fmaf(w4.z, Ml[part * 192 + t + 2], acc);
        acc = fmaf(w4.w, Ml[part * 192 + t + 3], acc);
    }
    ps[part][jj] = acc;
    __syncthreads();
    if (tid < 64)
        yseg[tid] = ps[0][tid] + ps[1][tid] + ps[2][tid] + ps[3][tid] + ob[jt * 64 + tid];
    __syncthreads();
    const int r0 = tid >> 2, c4 = (tid & 3) * 16;
    float4 v4[4];
#pragma unroll
    for (int q = 0; q < 4; ++q) v4[q] = *(const float4*)&yseg[c4 + q * 4];
    float* dst = out + ((size_t)(b * 1024 + rg * 64 + r0)) * 768 + jt * 64 + c4;
#pragma unroll
    for (int q = 0; q < 4; ++q) *(float4*)(dst + q * 4) = v4[q];
}

extern "C" void kernel_launch(void* const* d_in, const int* in_sizes, int n_in,
                              void* d_out, int out_size, void* d_ws, size_t ws_size,
                              hipStream_t stream) {
    const float* xs = (const float*)d_in[0];  // [2,1024,768]
    const float* ew = (const float*)d_in[1];  // [768,768]
    const float* eb = (const float*)d_in[2];  // [768]
    const float* nw = (const float*)d_in[3];  // [64,64]
    const float* ow = (const float*)d_in[4];  // [768,768]
    const float* ob = (const float*)d_in[5];  // [768]
    float* out = (float*)d_out;               // [2,1024,768]

    float* ws    = (float*)d_ws;
    float* h     = ws + 1572864;           // 1572864 f
    float* hri   = ws + 3145728;           // 1572864 f
    float* Wn    = ws + 4718592;           // 4096 f
    float* r1inv = ws + 4722688;           // 256 f
    float* mp0   = ws + 4722944;           // 24576 f
    float* mp1   = ws + 4747520;           // 24576 f
    float* mp2   = ws + 4772096;           // 24576 f
    float* c     = ws + 4796672;           // 24576 f
    ushort* xsH  = (ushort*)(ws + 4821248);    // 1572864 us (786432 f)
    ushort* xsL  = (ushort*)(ws + 5607680);    // 1572864 us
    ushort* ewH  = (ushort*)(ws + 6394112);    // 589824 us (294912 f)
    ushort* ewL  = (ushort*)(ws + 6689024);    // 589824 us
    ushort* Wfrag= (ushort*)(ws + 6983936);    // 16384 us (8192 f)

    k_conv<<<1057, 256, 0, stream>>>(xs, ew, nw, xsH, xsL, ewH, ewL, Wn, r1inv, Wfrag);
    k_embed_nnmf<<<384, 256, 0, stream>>>(xsH, xsL, ewH, ewL, eb, Wfrag, r1inv, h, hri, mp0);
    k_alpha_step<<<384, 256, 0, stream>>>(h, hri, Wn, mp0, mp1, c, 1);
    k_alpha_step<<<384, 256, 0, stream>>>(h, hri, Wn, mp1, mp2, c, 2);
    k_alpha_step<<<384, 256, 0, stream>>>(h, hri, Wn, mp2, mp1, c, 3);
    k_projbcast<<<384, 256, 0, stream>>>(mp1, ow, ob, out);
}